// Round 5
// baseline (313.199 us; speedup 1.0000x reference)
//
#include <hip/hip_runtime.h>

// Problem constants
#define BB 4
#define LLL 256
#define LPP 256
#define DDIM 256
#define HH 128

typedef _Float16 f16;
typedef f16 f16x8 __attribute__((ext_vector_type(8)));
typedef f16 f16x4 __attribute__((ext_vector_type(4)));
typedef float floatx4 __attribute__((ext_vector_type(4)));

__device__ __forceinline__ float gelu_f(float x) {
    return x / (1.f + __expf(-1.702f * x));
}
__device__ __forceinline__ float sigmoid_f(float x) {
    return 1.f / (1.f + __expf(-x));
}
__device__ __forceinline__ f16x8 habs8(f16x8 v) {
    uint4 u = __builtin_bit_cast(uint4, v);
    u.x &= 0x7fff7fffu; u.y &= 0x7fff7fffu; u.z &= 0x7fff7fffu; u.w &= 0x7fff7fffu;
    return __builtin_bit_cast(f16x8, u);
}
__device__ __forceinline__ unsigned okey(float f) {
    unsigned u = __float_as_uint(f);
    return (u & 0x80000000u) ? ~u : (u | 0x80000000u);
}

// ---------------------------------------------------------------------------
// Kernel 0: fragment-ordered f16 copies of W1c|W1d and (pi-permuted) W2.
// w1g chunk c (16B): c = ((ds*2+cd)*8+thg)*64 + quad*16 + m16
//   holds W1[h=thg*16+m16][512 + cd*256 + ds*32 + quad*8 + j], j=0..7
// w2g chunk c: c = (ks*8+tg)*64 + quad*16 + m16
//   holds W2[g=tg*16+m16][h = j*16 + ks*4 + quad]   (pi: k' = (h&15)*8 + (h>>4))
// ---------------------------------------------------------------------------
__global__ void cvt_w(const float* __restrict__ W1, const float* __restrict__ W2,
                      f16* __restrict__ w1g, f16* __restrict__ w2g) {
    int idx = blockIdx.x * 256 + threadIdx.x;
    if (idx < 8192) {
        int m16 = idx & 15, quad = (idx >> 4) & 3, th = (idx >> 6) & 7;
        int cd = (idx >> 9) & 1, ds = idx >> 10;
        int h = th * 16 + m16;
        const float* src = W1 + (size_t)h * 1024 + 512 + cd * 256 + ds * 32 + quad * 8;
        f16x8 v;
#pragma unroll
        for (int j = 0; j < 8; ++j) v[j] = (f16)src[j];
        *(f16x8*)(w1g + (size_t)idx * 8) = v;
    } else if (idx < 8192 + 2048) {
        int c = idx - 8192;
        int m16 = c & 15, quad = (c >> 4) & 3, tg = (c >> 6) & 7, ks = c >> 9;
        int g = tg * 16 + m16;
        f16x8 v;
#pragma unroll
        for (int j = 0; j < 8; ++j) v[j] = (f16)W2[g * HH + j * 16 + ks * 4 + quad];
        *(f16x8*)(w2g + (size_t)c * 8) = v;
    }
}

// ---------------------------------------------------------------------------
// Kernel 1: projections. proj[m][e], m in [0,1024): l rows, [1024,2048): p rows
// ---------------------------------------------------------------------------
__global__ __launch_bounds__(256) void prep_proj(
    const float* __restrict__ l_tok, const float* __restrict__ p_tok,
    const float* __restrict__ Wl, const float* __restrict__ Wp,
    const float* __restrict__ bl, const float* __restrict__ bp,
    f16* __restrict__ proj) {
    __shared__ __align__(16) char sm[2 * 64 * 80];
    f16* As = (f16*)sm;
    f16* Bs = (f16*)(sm + 64 * 80);
    int tid = threadIdx.x;
    int m0 = blockIdx.x * 64, n0 = blockIdx.y * 64;
    bool isP = (m0 >= 1024);
    const float* Asrc = isP ? (p_tok + (size_t)(m0 - 1024) * DDIM) : (l_tok + (size_t)m0 * DDIM);
    const float* Wsrc = isP ? Wp : Wl;
    const float* bias = isP ? bp : bl;
    int row = tid >> 2, seg = tid & 3;
    int w = tid >> 6, lane = tid & 63;
    int m16 = lane & 15, quad = lane >> 4;
    int wm = w & 1, wn = w >> 1;
    floatx4 acc[2][2];
#pragma unroll
    for (int a = 0; a < 2; ++a)
#pragma unroll
        for (int c = 0; c < 2; ++c) acc[a][c] = (floatx4)0.f;
    for (int k0 = 0; k0 < DDIM; k0 += 32) {
        float4 f0 = *(const float4*)(Asrc + row * DDIM + k0 + seg * 8);
        float4 f1 = *(const float4*)(Asrc + row * DDIM + k0 + seg * 8 + 4);
        f16x8 av;
        av[0] = (f16)f0.x; av[1] = (f16)f0.y; av[2] = (f16)f0.z; av[3] = (f16)f0.w;
        av[4] = (f16)f1.x; av[5] = (f16)f1.y; av[6] = (f16)f1.z; av[7] = (f16)f1.w;
        *(f16x8*)(As + row * 40 + seg * 8) = av;
        float4 g0 = *(const float4*)(Wsrc + (n0 + row) * DDIM + k0 + seg * 8);
        float4 g1 = *(const float4*)(Wsrc + (n0 + row) * DDIM + k0 + seg * 8 + 4);
        f16x8 bv;
        bv[0] = (f16)g0.x; bv[1] = (f16)g0.y; bv[2] = (f16)g0.z; bv[3] = (f16)g0.w;
        bv[4] = (f16)g1.x; bv[5] = (f16)g1.y; bv[6] = (f16)g1.z; bv[7] = (f16)g1.w;
        *(f16x8*)(Bs + row * 40 + seg * 8) = bv;
        __syncthreads();
        f16x8 afr[2], bfr[2];
#pragma unroll
        for (int t = 0; t < 2; ++t)
            afr[t] = *(const f16x8*)(As + (wm * 32 + t * 16 + m16) * 40 + quad * 8);
#pragma unroll
        for (int t = 0; t < 2; ++t)
            bfr[t] = *(const f16x8*)(Bs + (wn * 32 + t * 16 + m16) * 40 + quad * 8);
#pragma unroll
        for (int a = 0; a < 2; ++a)
#pragma unroll
            for (int c = 0; c < 2; ++c)
                acc[a][c] = __builtin_amdgcn_mfma_f32_16x16x32_f16(afr[a], bfr[c], acc[a][c], 0, 0, 0);
        __syncthreads();
    }
#pragma unroll
    for (int c = 0; c < 2; ++c) {
        int col = n0 + wn * 32 + c * 16 + m16;
        float bv = bias[col];
#pragma unroll
        for (int a = 0; a < 2; ++a) {
            int rbase = m0 + wm * 32 + a * 16 + quad * 4;
#pragma unroll
            for (int i = 0; i < 4; ++i)
                proj[(size_t)(rbase + i) * DDIM + col] = (f16)(acc[a][c][i] + bv);
        }
    }
}

// ---------------------------------------------------------------------------
// Kernel 2: A/Bp transposed. ABt[h][m] (fp32 [128][2048]).
// ---------------------------------------------------------------------------
__global__ __launch_bounds__(256) void prep_ab(
    const f16* __restrict__ proj, const float* __restrict__ W1,
    float* __restrict__ ABt) {
    __shared__ __align__(16) char sm[2 * 64 * 80];
    f16* As = (f16*)sm;
    f16* Bs = (f16*)(sm + 64 * 80);
    int tid = threadIdx.x;
    int m0 = blockIdx.x * 64, n0 = blockIdx.y * 64;
    bool isP = (m0 >= 1024);
    int koff = isP ? 256 : 0;
    int row = tid >> 2, seg = tid & 3;
    int w = tid >> 6, lane = tid & 63;
    int m16 = lane & 15, quad = lane >> 4;
    int wm = w & 1, wn = w >> 1;
    floatx4 acc[2][2];
#pragma unroll
    for (int a = 0; a < 2; ++a)
#pragma unroll
        for (int c = 0; c < 2; ++c) acc[a][c] = (floatx4)0.f;
    for (int k0 = 0; k0 < DDIM; k0 += 32) {
        f16x8 av = *(const f16x8*)(proj + (size_t)(m0 + row) * DDIM + k0 + seg * 8);
        *(f16x8*)(As + row * 40 + seg * 8) = av;
        float4 g0 = *(const float4*)(W1 + (size_t)(n0 + row) * 1024 + koff + k0 + seg * 8);
        float4 g1 = *(const float4*)(W1 + (size_t)(n0 + row) * 1024 + koff + k0 + seg * 8 + 4);
        f16x8 bv;
        bv[0] = (f16)g0.x; bv[1] = (f16)g0.y; bv[2] = (f16)g0.z; bv[3] = (f16)g0.w;
        bv[4] = (f16)g1.x; bv[5] = (f16)g1.y; bv[6] = (f16)g1.z; bv[7] = (f16)g1.w;
        *(f16x8*)(Bs + row * 40 + seg * 8) = bv;
        __syncthreads();
        f16x8 afr[2], bfr[2];
#pragma unroll
        for (int t = 0; t < 2; ++t)
            afr[t] = *(const f16x8*)(As + (wm * 32 + t * 16 + m16) * 40 + quad * 8);
#pragma unroll
        for (int t = 0; t < 2; ++t)
            bfr[t] = *(const f16x8*)(Bs + (wn * 32 + t * 16 + m16) * 40 + quad * 8);
#pragma unroll
        for (int a = 0; a < 2; ++a)
#pragma unroll
            for (int c = 0; c < 2; ++c)
                acc[a][c] = __builtin_amdgcn_mfma_f32_16x16x32_f16(afr[a], bfr[c], acc[a][c], 0, 0, 0);
        __syncthreads();
    }
#pragma unroll
    for (int c = 0; c < 2; ++c) {
        int col = n0 + wn * 32 + c * 16 + m16;
#pragma unroll
        for (int a = 0; a < 2; ++a) {
            int rbase = m0 + wm * 32 + a * 16 + quad * 4;
#pragma unroll
            for (int i = 0; i < 4; ++i)
                ABt[(size_t)col * 2048 + rbase + i] = acc[a][c][i];
        }
    }
}

// ---------------------------------------------------------------------------
// Kernel 3: main pair kernel. 512 threads = 8 waves, block = ONE l-row.
// Wave w: wp = w&3 (64 p), wh = w>>2 (64 h). acc 4x4 = 64 regs.
// K-loop barrier-free: A-frags register-generated from global proj; B-frags
// (W1c/W1d) read straight from GLOBAL w1g (lane-linear 1 KB/wave, L1/L2-hot,
// shared by every block). No W1 LDS -> LDS 70.7 KB -> 2 blocks/CU, 4 w/SIMD.
// ---------------------------------------------------------------------------
#define H1_STRIDE 272
#define SM_PLOG (256 * H1_STRIDE)
#define SM_TOTAL (SM_PLOG + 1024)

__global__ __launch_bounds__(512, 4) void pair_main(
    const f16* __restrict__ proj, const float* __restrict__ ABt,
    const f16* __restrict__ w1g, const f16* __restrict__ w2g,
    const float* __restrict__ b1, const float* __restrict__ b2,
    const float* __restrict__ W3, const float* __restrict__ b3,
    const int* __restrict__ l_pad, const int* __restrict__ p_pad,
    float* __restrict__ out) {
    __shared__ __align__(16) char sm[SM_TOTAL];
    int tid = threadIdx.x;
    int lane = tid & 63, w = tid >> 6;
    int m16 = lane & 15, quad = lane >> 4;
    int wp = w & 3, wh = w >> 2;
    int p0 = wp * 64, h0 = wh * 64;
    int b = blockIdx.y;
    int l = blockIdx.x;
    int ml = b * LLL + l;
    float* outPL = out + 4;
    float* outPR = out + 4 + BB * LLL * LPP;
    size_t rowbase = (size_t)ml * LPP;

    if (l_pad[ml] != 0) {  // wave-uniform across block
        float pr = sigmoid_f(-20.f);
        if (tid < LPP) {
            outPL[rowbase + tid] = -20.f;
            outPR[rowbase + tid] = pr;
        }
        return;
    }

    float* plog = (float*)(sm + SM_PLOG);
    char* h1s = sm;
    if (tid < 256) plog[tid] = 0.f;

    // accumulator init: A[l,h] + b1[h] + Bp[p,h]
    floatx4 acc[4][4];
    {
        float av[4];
#pragma unroll
        for (int th = 0; th < 4; ++th) {
            int hh = h0 + th * 16 + m16;
            av[th] = ABt[(size_t)hh * 2048 + ml] + b1[hh];
        }
#pragma unroll
        for (int tp = 0; tp < 4; ++tp) {
            int rp = p0 + tp * 16 + quad * 4;
#pragma unroll
            for (int th = 0; th < 4; ++th) {
                int hh = h0 + th * 16 + m16;
                floatx4 bp4 = *(const floatx4*)(ABt + (size_t)hh * 2048 + 1024 + b * LPP + rp);
                floatx4 a;
#pragma unroll
                for (int i = 0; i < 4; ++i) a[i] = bp4[i] + av[th];
                acc[tp][th] = a;
            }
        }
    }

    // GEMM1 K-loop: barrier-free; W1 B-frags from global (L1/L2-hot)
    {
        const f16* Lr = proj + (size_t)ml * DDIM + quad * 8;
        const f16* Pr = proj + (size_t)(1024 + b * LPP) * DDIM + quad * 8;
        const f16* Wbase = w1g + (size_t)(wh * 4) * 1024 + lane * 8;  // chunk*8 f16
        for (int ds = 0; ds < 8; ++ds) {
            f16x8 lv = *(const f16x8*)(Lr + ds * 32);
            f16x8 pv[4];
#pragma unroll
            for (int tp = 0; tp < 4; ++tp)
                pv[tp] = *(const f16x8*)(Pr + (size_t)(p0 + tp * 16 + m16) * DDIM + ds * 32);
            // c-half: x1 = l*p vs W1c
            {
                const f16* wb = Wbase + (size_t)(ds * 2 + 0) * 8192;
                f16x8 x[4];
#pragma unroll
                for (int tp = 0; tp < 4; ++tp) x[tp] = lv * pv[tp];
#pragma unroll
                for (int th = 0; th < 4; ++th) {
                    f16x8 bf = *(const f16x8*)(wb + th * 1024);
#pragma unroll
                    for (int tp = 0; tp < 4; ++tp)
                        acc[tp][th] = __builtin_amdgcn_mfma_f32_16x16x32_f16(x[tp], bf, acc[tp][th], 0, 0, 0);
                }
            }
            // d-half: x2 = |l-p| vs W1d
            {
                const f16* wb = Wbase + (size_t)(ds * 2 + 1) * 8192;
                f16x8 x[4];
#pragma unroll
                for (int tp = 0; tp < 4; ++tp) x[tp] = habs8(lv - pv[tp]);
#pragma unroll
                for (int th = 0; th < 4; ++th) {
                    f16x8 bf = *(const f16x8*)(wb + th * 1024);
#pragma unroll
                    for (int tp = 0; tp < 4; ++tp)
                        acc[tp][th] = __builtin_amdgcn_mfma_f32_16x16x32_f16(x[tp], bf, acc[tp][th], 0, 0, 0);
                }
            }
        }
    }

    // h1' (pi-space): k' = m16*8 + wh*4 + th -> b64 writes
#pragma unroll
    for (int tp = 0; tp < 4; ++tp) {
#pragma unroll
        for (int i = 0; i < 4; ++i) {
            f16x4 hv;
#pragma unroll
            for (int th = 0; th < 4; ++th) hv[th] = (f16)gelu_f(acc[tp][th][i]);
            int p = p0 + tp * 16 + quad * 4 + i;
            *(f16x4*)(h1s + p * H1_STRIDE + m16 * 16 + wh * 8) = hv;
        }
    }
    __syncthreads();

    // GEMM2: wave 64p x 64g, K'=128 (W2 pre-permuted in w2g, global L1-hot)
    float b2v[4], w3v[4];
#pragma unroll
    for (int th = 0; th < 4; ++th) {
        int g = h0 + th * 16 + m16;
        b2v[th] = b2[g];
        w3v[th] = W3[g];
    }
    floatx4 acc2[4][4];
#pragma unroll
    for (int tp = 0; tp < 4; ++tp)
#pragma unroll
        for (int th = 0; th < 4; ++th) {
            floatx4 a;
            a[0] = a[1] = a[2] = a[3] = b2v[th];
            acc2[tp][th] = a;
        }
#pragma unroll
    for (int ks = 0; ks < 4; ++ks) {
        f16x8 af[4];
#pragma unroll
        for (int tp = 0; tp < 4; ++tp)
            af[tp] = *(const f16x8*)(h1s + (p0 + tp * 16 + m16) * H1_STRIDE + ks * 64 + quad * 16);
#pragma unroll
        for (int th = 0; th < 4; ++th) {
            f16x8 bf = *(const f16x8*)(w2g + (size_t)(((ks * 8 + wh * 4 + th) * 4 + quad) * 16 + m16) * 8);
#pragma unroll
            for (int tp = 0; tp < 4; ++tp)
                acc2[tp][th] = __builtin_amdgcn_mfma_f32_16x16x32_f16(af[tp], bf, acc2[tp][th], 0, 0, 0);
        }
    }

    // epilogue: gelu, W3 partial dot (64 g), reduce over m16, combine wh via plog
    float part[16];
#pragma unroll
    for (int j = 0; j < 16; ++j) part[j] = 0.f;
#pragma unroll
    for (int tp = 0; tp < 4; ++tp)
#pragma unroll
        for (int th = 0; th < 4; ++th)
#pragma unroll
            for (int i = 0; i < 4; ++i)
                part[tp * 4 + i] += w3v[th] * gelu_f(acc2[tp][th][i]);
#pragma unroll
    for (int mask = 1; mask <= 8; mask <<= 1)
#pragma unroll
        for (int j = 0; j < 16; ++j) part[j] += __shfl_xor(part[j], mask, 64);
    if (m16 == 0) {
#pragma unroll
        for (int tp = 0; tp < 4; ++tp)
#pragma unroll
            for (int i = 0; i < 4; ++i)
                atomicAdd(&plog[p0 + tp * 16 + quad * 4 + i], part[tp * 4 + i]);
    }
    __syncthreads();

    if (tid < LPP) {
        int p = tid;
        float pl = plog[p] + b3[0];
        if (__builtin_isnan(pl)) pl = 0.f;
        else if (__builtin_isinf(pl)) pl = pl > 0.f ? 20.f : -20.f;
        if (p_pad[b * LPP + p] != 0) pl = -20.f;
        outPL[rowbase + p] = pl;
        outPR[rowbase + p] = sigmoid_f(pl);
    }
}

// ---------------------------------------------------------------------------
// Kernel 4: top-100 + softmax pool per batch. 3-pass radix (24-bit prefix);
// boundary ties merged at midpoint value (error < 1e-4, threshold 0.4).
// ---------------------------------------------------------------------------
__global__ __launch_bounds__(1024) void topk_k(const float* __restrict__ pl,
                                               float* __restrict__ out) {
    __shared__ int hist[16 * 256];
    __shared__ float redf[32];
    __shared__ unsigned bc_pref;
    __shared__ int bc_rem;
    __shared__ float bc_vmax;
    int b = blockIdx.x, tid = threadIdx.x;
    int wv = tid >> 6, lane = tid & 63;
    const float4* src = (const float4*)(pl + (size_t)b * 65536);

#pragma unroll
    for (int r = 0; r < 4; ++r) hist[tid + r * 1024] = 0;
    __syncthreads();

    float mx = -1e30f;
    int c20 = 0;
    const unsigned bin20 = okey(-20.f) >> 24;
    {
        int rep = wv * 256;
        for (int j = 0; j < 16; ++j) {
            float4 t = src[tid + j * 1024];
#pragma unroll
            for (int c = 0; c < 4; ++c) {
                float v = (&t.x)[c];
                mx = fmaxf(mx, v);
                if (v == -20.f) c20++;
                else atomicAdd(&hist[rep + (okey(v) >> 24)], 1);
            }
        }
        atomicAdd(&hist[rep + bin20], c20);
    }
    for (int off = 32; off > 0; off >>= 1) mx = fmaxf(mx, __shfl_xor(mx, off, 64));
    if (lane == 0) redf[wv] = mx;
    __syncthreads();
    if (tid < 256) {
        int s = 0;
#pragma unroll
        for (int ww = 0; ww < 16; ++ww) s += hist[ww * 256 + tid];
        hist[tid] = s;
    }
    __syncthreads();
    if (tid == 0) {
        float m = redf[0];
        for (int i = 1; i < 16; ++i) m = fmaxf(m, redf[i]);
        bc_vmax = m;
        int cum = 0, chosen = 0, above = 0;
        for (int bin = 255; bin >= 0; --bin) {
            int c = hist[bin];
            if (cum + c >= 100) { chosen = bin; above = cum; break; }
            cum += c;
        }
        bc_pref = (unsigned)chosen;
        bc_rem = 100 - above;
    }
    __syncthreads();
    unsigned pref = bc_pref;
    int rem = bc_rem;

    for (int pass = 1; pass < 3; ++pass) {
        if (tid < 512) hist[tid] = 0;
        __syncthreads();
        int sh = 24 - 8 * pass;
        int rep = (wv & 1) * 256;
        for (int j = 0; j < 16; ++j) {
            float4 t = src[tid + j * 1024];
#pragma unroll
            for (int c = 0; c < 4; ++c) {
                unsigned u = okey((&t.x)[c]);
                if ((u >> (sh + 8)) == pref) atomicAdd(&hist[rep + ((u >> sh) & 255)], 1);
            }
        }
        __syncthreads();
        if (tid == 0) {
            int cum = 0, chosen = 0, above = 0;
            for (int bin = 255; bin >= 0; --bin) {
                int c = hist[bin] + hist[bin + 256];
                if (cum + c >= rem) { chosen = bin; above = cum; break; }
                cum += c;
            }
            bc_pref = (pref << 8) | (unsigned)chosen;
            bc_rem = rem - above;
        }
        __syncthreads();
        pref = bc_pref;
        rem = bc_rem;
        __syncthreads();
    }

    // pref is 24-bit prefix. Include all keys with (key>>8) > pref fully,
    // plus rem boundary elements at the bin's midpoint value.
    float vmax = bc_vmax;
    float s1 = 0.f, s2 = 0.f;
    for (int j = 0; j < 16; ++j) {
        float4 t = src[tid + j * 1024];
#pragma unroll
        for (int c = 0; c < 4; ++c) {
            float v = (&t.x)[c];
            if ((okey(v) >> 8) > pref) {
                float e = __expf(v - vmax);
                s1 += e;
                s2 += e * v;
            }
        }
    }
    for (int off = 32; off > 0; off >>= 1) {
        s1 += __shfl_xor(s1, off, 64);
        s2 += __shfl_xor(s2, off, 64);
    }
    if (lane == 0) { redf[wv] = s1; redf[16 + wv] = s2; }
    __syncthreads();
    if (tid == 0) {
        float t1 = 0.f, t2 = 0.f;
        for (int i = 0; i < 16; ++i) { t1 += redf[i]; t2 += redf[16 + i]; }
        unsigned key = (pref << 8) | 0x80u;  // midpoint of boundary bin
        unsigned bits = (key & 0x80000000u) ? (key & 0x7fffffffu) : ~key;
        float vT = __uint_as_float(bits);
        float e = __expf(vT - vmax);
        t1 += (float)rem * e;
        t2 += (float)rem * e * vT;
        out[b] = t2 / t1;
    }
}

// ---------------------------------------------------------------------------
extern "C" void kernel_launch(void* const* d_in, const int* in_sizes, int n_in,
                              void* d_out, int out_size, void* d_ws, size_t ws_size,
                              hipStream_t stream) {
    const float* l_tok = (const float*)d_in[0];
    const float* p_tok = (const float*)d_in[1];
    const int* l_pad = (const int*)d_in[2];
    const int* p_pad = (const int*)d_in[3];
    const float* Wl = (const float*)d_in[4];
    const float* bl = (const float*)d_in[5];
    const float* Wp = (const float*)d_in[6];
    const float* bp = (const float*)d_in[7];
    const float* W1 = (const float*)d_in[8];
    const float* b1 = (const float*)d_in[9];
    const float* W2 = (const float*)d_in[10];
    const float* b2 = (const float*)d_in[11];
    const float* W3 = (const float*)d_in[12];
    const float* b3 = (const float*)d_in[13];
    float* out = (float*)d_out;

    char* ws = (char*)d_ws;
    f16* proj = (f16*)ws;                                       // 2048*256 f16 = 1 MiB
    float* ABt = (float*)(ws + (size_t)2048 * 256 * 2);         // 128*2048 f32 = 1 MiB
    f16* w1g = (f16*)(ws + (size_t)2048 * 256 * 2 + (size_t)128 * 2048 * 4);  // 128 KiB
    f16* w2g = (f16*)((char*)w1g + (size_t)8192 * 16);          // 32 KiB

    cvt_w<<<40, 256, 0, stream>>>(W1, W2, w1g, w2g);
    prep_proj<<<dim3(32, 4), 256, 0, stream>>>(l_tok, p_tok, Wl, Wp, bl, bp, proj);
    prep_ab<<<dim3(32, 2), 256, 0, stream>>>(proj, W1, ABt);
    pair_main<<<dim3(LLL, BB), 512, 0, stream>>>(proj, ABt, w1g, w2g, b1, b2, W3, b3,
                                                 l_pad, p_pad, out);
    topk_k<<<BB, 1024, 0, stream>>>(out + 4, out);
}

// Round 6
// 230.096 us; speedup vs baseline: 1.3612x; 1.3612x over previous
//
#include <hip/hip_runtime.h>

// Problem constants
#define BB 4
#define LLL 256
#define LPP 256
#define DDIM 256
#define HH 128

typedef _Float16 f16;
typedef f16 f16x8 __attribute__((ext_vector_type(8)));
typedef f16 f16x4 __attribute__((ext_vector_type(4)));
typedef float floatx4 __attribute__((ext_vector_type(4)));

__device__ __forceinline__ float gelu_f(float x) {
    return x / (1.f + __expf(-1.702f * x));
}
__device__ __forceinline__ float sigmoid_f(float x) {
    return 1.f / (1.f + __expf(-x));
}
__device__ __forceinline__ f16x8 habs8(f16x8 v) {
    uint4 u = __builtin_bit_cast(uint4, v);
    u.x &= 0x7fff7fffu; u.y &= 0x7fff7fffu; u.z &= 0x7fff7fffu; u.w &= 0x7fff7fffu;
    return __builtin_bit_cast(f16x8, u);
}
__device__ __forceinline__ unsigned okey(float f) {
    unsigned u = __float_as_uint(f);
    return (u & 0x80000000u) ? ~u : (u | 0x80000000u);
}

// ---------------------------------------------------------------------------
// Kernel 0: fragment-ordered f16 copies of W1c|W1d and (pi-permuted) W2.
// w1g chunk c (16B): c = ((ds*2+cd)*8+thg)*64 + quad*16 + m16
//   holds W1[h=thg*16+m16][512 + cd*256 + ds*32 + quad*8 + j], j=0..7
// w2g chunk c: c = (ks*8+tg)*64 + quad*16 + m16
//   holds W2[g=tg*16+m16][h = j*16 + ks*4 + quad]   (pi: k' = (h&15)*8 + (h>>4))
// ---------------------------------------------------------------------------
__global__ void cvt_w(const float* __restrict__ W1, const float* __restrict__ W2,
                      f16* __restrict__ w1g, f16* __restrict__ w2g) {
    int idx = blockIdx.x * 256 + threadIdx.x;
    if (idx < 8192) {
        int m16 = idx & 15, quad = (idx >> 4) & 3, th = (idx >> 6) & 7;
        int cd = (idx >> 9) & 1, ds = idx >> 10;
        int h = th * 16 + m16;
        const float* src = W1 + (size_t)h * 1024 + 512 + cd * 256 + ds * 32 + quad * 8;
        f16x8 v;
#pragma unroll
        for (int j = 0; j < 8; ++j) v[j] = (f16)src[j];
        *(f16x8*)(w1g + (size_t)idx * 8) = v;
    } else if (idx < 8192 + 2048) {
        int c = idx - 8192;
        int m16 = c & 15, quad = (c >> 4) & 3, tg = (c >> 6) & 7, ks = c >> 9;
        int g = tg * 16 + m16;
        f16x8 v;
#pragma unroll
        for (int j = 0; j < 8; ++j) v[j] = (f16)W2[g * HH + j * 16 + ks * 4 + quad];
        *(f16x8*)(w2g + (size_t)c * 8) = v;
    }
}

// ---------------------------------------------------------------------------
// Kernel 1: projections. proj[m][e], m in [0,1024): l rows, [1024,2048): p rows
// ---------------------------------------------------------------------------
__global__ __launch_bounds__(256) void prep_proj(
    const float* __restrict__ l_tok, const float* __restrict__ p_tok,
    const float* __restrict__ Wl, const float* __restrict__ Wp,
    const float* __restrict__ bl, const float* __restrict__ bp,
    f16* __restrict__ proj) {
    __shared__ __align__(16) char sm[2 * 64 * 80];
    f16* As = (f16*)sm;
    f16* Bs = (f16*)(sm + 64 * 80);
    int tid = threadIdx.x;
    int m0 = blockIdx.x * 64, n0 = blockIdx.y * 64;
    bool isP = (m0 >= 1024);
    const float* Asrc = isP ? (p_tok + (size_t)(m0 - 1024) * DDIM) : (l_tok + (size_t)m0 * DDIM);
    const float* Wsrc = isP ? Wp : Wl;
    const float* bias = isP ? bp : bl;
    int row = tid >> 2, seg = tid & 3;
    int w = tid >> 6, lane = tid & 63;
    int m16 = lane & 15, quad = lane >> 4;
    int wm = w & 1, wn = w >> 1;
    floatx4 acc[2][2];
#pragma unroll
    for (int a = 0; a < 2; ++a)
#pragma unroll
        for (int c = 0; c < 2; ++c) acc[a][c] = (floatx4)0.f;
    for (int k0 = 0; k0 < DDIM; k0 += 32) {
        float4 f0 = *(const float4*)(Asrc + row * DDIM + k0 + seg * 8);
        float4 f1 = *(const float4*)(Asrc + row * DDIM + k0 + seg * 8 + 4);
        f16x8 av;
        av[0] = (f16)f0.x; av[1] = (f16)f0.y; av[2] = (f16)f0.z; av[3] = (f16)f0.w;
        av[4] = (f16)f1.x; av[5] = (f16)f1.y; av[6] = (f16)f1.z; av[7] = (f16)f1.w;
        *(f16x8*)(As + row * 40 + seg * 8) = av;
        float4 g0 = *(const float4*)(Wsrc + (n0 + row) * DDIM + k0 + seg * 8);
        float4 g1 = *(const float4*)(Wsrc + (n0 + row) * DDIM + k0 + seg * 8 + 4);
        f16x8 bv;
        bv[0] = (f16)g0.x; bv[1] = (f16)g0.y; bv[2] = (f16)g0.z; bv[3] = (f16)g0.w;
        bv[4] = (f16)g1.x; bv[5] = (f16)g1.y; bv[6] = (f16)g1.z; bv[7] = (f16)g1.w;
        *(f16x8*)(Bs + row * 40 + seg * 8) = bv;
        __syncthreads();
        f16x8 afr[2], bfr[2];
#pragma unroll
        for (int t = 0; t < 2; ++t)
            afr[t] = *(const f16x8*)(As + (wm * 32 + t * 16 + m16) * 40 + quad * 8);
#pragma unroll
        for (int t = 0; t < 2; ++t)
            bfr[t] = *(const f16x8*)(Bs + (wn * 32 + t * 16 + m16) * 40 + quad * 8);
#pragma unroll
        for (int a = 0; a < 2; ++a)
#pragma unroll
            for (int c = 0; c < 2; ++c)
                acc[a][c] = __builtin_amdgcn_mfma_f32_16x16x32_f16(afr[a], bfr[c], acc[a][c], 0, 0, 0);
        __syncthreads();
    }
#pragma unroll
    for (int c = 0; c < 2; ++c) {
        int col = n0 + wn * 32 + c * 16 + m16;
        float bv = bias[col];
#pragma unroll
        for (int a = 0; a < 2; ++a) {
            int rbase = m0 + wm * 32 + a * 16 + quad * 4;
#pragma unroll
            for (int i = 0; i < 4; ++i)
                proj[(size_t)(rbase + i) * DDIM + col] = (f16)(acc[a][c][i] + bv);
        }
    }
}

// ---------------------------------------------------------------------------
// Kernel 2: A/Bp transposed. ABt[h][m] (fp32 [128][2048]).
// ---------------------------------------------------------------------------
__global__ __launch_bounds__(256) void prep_ab(
    const f16* __restrict__ proj, const float* __restrict__ W1,
    float* __restrict__ ABt) {
    __shared__ __align__(16) char sm[2 * 64 * 80];
    f16* As = (f16*)sm;
    f16* Bs = (f16*)(sm + 64 * 80);
    int tid = threadIdx.x;
    int m0 = blockIdx.x * 64, n0 = blockIdx.y * 64;
    bool isP = (m0 >= 1024);
    int koff = isP ? 256 : 0;
    int row = tid >> 2, seg = tid & 3;
    int w = tid >> 6, lane = tid & 63;
    int m16 = lane & 15, quad = lane >> 4;
    int wm = w & 1, wn = w >> 1;
    floatx4 acc[2][2];
#pragma unroll
    for (int a = 0; a < 2; ++a)
#pragma unroll
        for (int c = 0; c < 2; ++c) acc[a][c] = (floatx4)0.f;
    for (int k0 = 0; k0 < DDIM; k0 += 32) {
        f16x8 av = *(const f16x8*)(proj + (size_t)(m0 + row) * DDIM + k0 + seg * 8);
        *(f16x8*)(As + row * 40 + seg * 8) = av;
        float4 g0 = *(const float4*)(W1 + (size_t)(n0 + row) * 1024 + koff + k0 + seg * 8);
        float4 g1 = *(const float4*)(W1 + (size_t)(n0 + row) * 1024 + koff + k0 + seg * 8 + 4);
        f16x8 bv;
        bv[0] = (f16)g0.x; bv[1] = (f16)g0.y; bv[2] = (f16)g0.z; bv[3] = (f16)g0.w;
        bv[4] = (f16)g1.x; bv[5] = (f16)g1.y; bv[6] = (f16)g1.z; bv[7] = (f16)g1.w;
        *(f16x8*)(Bs + row * 40 + seg * 8) = bv;
        __syncthreads();
        f16x8 afr[2], bfr[2];
#pragma unroll
        for (int t = 0; t < 2; ++t)
            afr[t] = *(const f16x8*)(As + (wm * 32 + t * 16 + m16) * 40 + quad * 8);
#pragma unroll
        for (int t = 0; t < 2; ++t)
            bfr[t] = *(const f16x8*)(Bs + (wn * 32 + t * 16 + m16) * 40 + quad * 8);
#pragma unroll
        for (int a = 0; a < 2; ++a)
#pragma unroll
            for (int c = 0; c < 2; ++c)
                acc[a][c] = __builtin_amdgcn_mfma_f32_16x16x32_f16(afr[a], bfr[c], acc[a][c], 0, 0, 0);
        __syncthreads();
    }
#pragma unroll
    for (int c = 0; c < 2; ++c) {
        int col = n0 + wn * 32 + c * 16 + m16;
#pragma unroll
        for (int a = 0; a < 2; ++a) {
            int rbase = m0 + wm * 32 + a * 16 + quad * 4;
#pragma unroll
            for (int i = 0; i < 4; ++i)
                ABt[(size_t)col * 2048 + rbase + i] = acc[a][c][i];
        }
    }
}

// ---------------------------------------------------------------------------
// Kernel 3: main pair kernel. 512 threads = 8 waves, block = TWO l-rows.
// Wave w: wp = w&3 (64 p), wh = w>>2 (64 h); each wave computes BOTH l-rows
// (acc[2][4][4] = 128 AGPR) so pv / W1-frag staging is amortized over 128
// MFMA per ds-step. K-loop barrier-free, register double-buffer on pv/lv.
// LDS: W1 frag-ordered 128 KB (staged once), overlaid after K-loop by
// h1' (2 x 256 x 272 B, conflict-free stride); plog 2 KB. 1 block/CU.
// ---------------------------------------------------------------------------
#define H1_STRIDE 272
#define SM_PLOG 139264
#define SM_TOTAL 141312

__global__ __launch_bounds__(512, 2) void pair_main(
    const f16* __restrict__ proj, const float* __restrict__ ABt,
    const f16* __restrict__ w1g, const f16* __restrict__ w2g,
    const float* __restrict__ b1, const float* __restrict__ b2,
    const float* __restrict__ W3, const float* __restrict__ b3,
    const int* __restrict__ l_pad, const int* __restrict__ p_pad,
    float* __restrict__ out) {
    __shared__ __align__(16) char sm[SM_TOTAL];
    int tid = threadIdx.x;
    int lane = tid & 63, w = tid >> 6;
    int m16 = lane & 15, quad = lane >> 4;
    int wp = w & 3, wh = w >> 2;
    int p0 = wp * 64, h0 = wh * 64;
    int b = blockIdx.y;
    int l0 = blockIdx.x * 2;
    int ml0 = b * LLL + l0;
    float* outPL = out + 4;
    float* outPR = out + 4 + BB * LLL * LPP;

    bool pad0 = (l_pad[ml0] != 0), pad1 = (l_pad[ml0 + 1] != 0);
    if (pad0 && pad1) {  // block-uniform fast path
        float pr = sigmoid_f(-20.f);
        if (tid < 512) {
            int j = tid >> 8, p = tid & 255;
            outPL[(size_t)(ml0 + j) * LPP + p] = -20.f;
            outPR[(size_t)(ml0 + j) * LPP + p] = pr;
        }
        return;
    }

    float* plog = (float*)(sm + SM_PLOG);

    // stage fragment-ordered W1c|W1d into LDS (linear 128 KB copy)
#pragma unroll
    for (int r = 0; r < 16; ++r) {
        int c = tid + r * 512;
        *(f16x8*)(sm + c * 16) = *(const f16x8*)(w1g + (size_t)c * 8);
    }
    if (tid < 512) plog[tid] = 0.f;

    // accumulator init: A[l_j,h] + b1[h] + Bp[p,h]  (Bp shared across j)
    floatx4 acc[2][4][4];
    {
        float av[2][4];
#pragma unroll
        for (int th = 0; th < 4; ++th) {
            int hh = h0 + th * 16 + m16;
            float base = b1[hh];
            av[0][th] = ABt[(size_t)hh * 2048 + ml0] + base;
            av[1][th] = ABt[(size_t)hh * 2048 + ml0 + 1] + base;
        }
#pragma unroll
        for (int tp = 0; tp < 4; ++tp) {
            int rp = p0 + tp * 16 + quad * 4;
#pragma unroll
            for (int th = 0; th < 4; ++th) {
                int hh = h0 + th * 16 + m16;
                floatx4 bp4 = *(const floatx4*)(ABt + (size_t)hh * 2048 + 1024 + b * LPP + rp);
#pragma unroll
                for (int j = 0; j < 2; ++j) {
                    floatx4 a;
#pragma unroll
                    for (int i = 0; i < 4; ++i) a[i] = bp4[i] + av[j][th];
                    acc[j][tp][th] = a;
                }
            }
        }
    }
    __syncthreads();

    // GEMM1 K-loop: barrier-free, 128 MFMA per ds, pv/lv double-buffered
    {
        const f16* Lr0 = proj + (size_t)ml0 * DDIM + quad * 8;
        const f16* Lr1 = Lr0 + DDIM;
        const f16* Prl[4];
#pragma unroll
        for (int tp = 0; tp < 4; ++tp)
            Prl[tp] = proj + (size_t)(1024 + b * LPP + p0 + tp * 16 + m16) * DDIM + quad * 8;

        f16x8 lv0 = *(const f16x8*)(Lr0);
        f16x8 lv1 = *(const f16x8*)(Lr1);
        f16x8 pv[4];
#pragma unroll
        for (int tp = 0; tp < 4; ++tp) pv[tp] = *(const f16x8*)(Prl[tp]);

        for (int ds = 0; ds < 8; ++ds) {
            f16x8 nlv0, nlv1, npv[4];
            if (ds < 7) {
                nlv0 = *(const f16x8*)(Lr0 + (ds + 1) * 32);
                nlv1 = *(const f16x8*)(Lr1 + (ds + 1) * 32);
#pragma unroll
                for (int tp = 0; tp < 4; ++tp)
                    npv[tp] = *(const f16x8*)(Prl[tp] + (ds + 1) * 32);
            }
            const char* wb = sm + (size_t)(ds * 2) * 8192 + (wh * 4) * 1024 + quad * 256 + m16 * 16;
            // c-half: x = l*p vs W1c
            {
                f16x8 x[2][4];
#pragma unroll
                for (int tp = 0; tp < 4; ++tp) {
                    x[0][tp] = lv0 * pv[tp];
                    x[1][tp] = lv1 * pv[tp];
                }
#pragma unroll
                for (int th = 0; th < 4; ++th) {
                    f16x8 bf = *(const f16x8*)(wb + th * 1024);
#pragma unroll
                    for (int j = 0; j < 2; ++j)
#pragma unroll
                        for (int tp = 0; tp < 4; ++tp)
                            acc[j][tp][th] = __builtin_amdgcn_mfma_f32_16x16x32_f16(x[j][tp], bf, acc[j][tp][th], 0, 0, 0);
                }
            }
            // d-half: x = |l-p| vs W1d
            {
                f16x8 x[2][4];
#pragma unroll
                for (int tp = 0; tp < 4; ++tp) {
                    x[0][tp] = habs8(lv0 - pv[tp]);
                    x[1][tp] = habs8(lv1 - pv[tp]);
                }
#pragma unroll
                for (int th = 0; th < 4; ++th) {
                    f16x8 bf = *(const f16x8*)(wb + 8192 + th * 1024);
#pragma unroll
                    for (int j = 0; j < 2; ++j)
#pragma unroll
                        for (int tp = 0; tp < 4; ++tp)
                            acc[j][tp][th] = __builtin_amdgcn_mfma_f32_16x16x32_f16(x[j][tp], bf, acc[j][tp][th], 0, 0, 0);
                }
            }
            lv0 = nlv0; lv1 = nlv1;
#pragma unroll
            for (int tp = 0; tp < 4; ++tp) pv[tp] = npv[tp];
        }
    }
    __syncthreads();  // all waves done reading W1 LDS before h1 overlay

    // h1' (pi-space) overlay: k' = m16*8 + wh*4 + th  -> byte m16*16 + wh*8
#pragma unroll
    for (int j = 0; j < 2; ++j) {
        char* h1s = sm + j * (256 * H1_STRIDE);
#pragma unroll
        for (int tp = 0; tp < 4; ++tp) {
#pragma unroll
            for (int i = 0; i < 4; ++i) {
                f16x4 hv;
#pragma unroll
                for (int th = 0; th < 4; ++th) hv[th] = (f16)gelu_f(acc[j][tp][th][i]);
                int p = p0 + tp * 16 + quad * 4 + i;
                *(f16x4*)(h1s + p * H1_STRIDE + m16 * 16 + wh * 8) = hv;
            }
        }
    }
    __syncthreads();

    // GEMM2: wave 2l x 64p x 64g, K'=128 (W2 pre-permuted in w2g, L1-hot)
    float b2v[4], w3v[4];
#pragma unroll
    for (int th = 0; th < 4; ++th) {
        int g = h0 + th * 16 + m16;
        b2v[th] = b2[g];
        w3v[th] = W3[g];
    }
    floatx4 acc2[2][4][4];
#pragma unroll
    for (int j = 0; j < 2; ++j)
#pragma unroll
        for (int tp = 0; tp < 4; ++tp)
#pragma unroll
            for (int th = 0; th < 4; ++th) {
                floatx4 a;
                a[0] = a[1] = a[2] = a[3] = b2v[th];
                acc2[j][tp][th] = a;
            }
#pragma unroll
    for (int ks = 0; ks < 4; ++ks) {
        f16x8 af[2][4];
#pragma unroll
        for (int j = 0; j < 2; ++j)
#pragma unroll
            for (int tp = 0; tp < 4; ++tp)
                af[j][tp] = *(const f16x8*)(sm + j * (256 * H1_STRIDE) +
                                            (p0 + tp * 16 + m16) * H1_STRIDE + ks * 64 + quad * 16);
#pragma unroll
        for (int th = 0; th < 4; ++th) {
            f16x8 bf = *(const f16x8*)(w2g + (size_t)(((ks * 8 + wh * 4 + th) * 4 + quad) * 16 + m16) * 8);
#pragma unroll
            for (int j = 0; j < 2; ++j)
#pragma unroll
                for (int tp = 0; tp < 4; ++tp)
                    acc2[j][tp][th] = __builtin_amdgcn_mfma_f32_16x16x32_f16(af[j][tp], bf, acc2[j][tp][th], 0, 0, 0);
        }
    }

    // epilogue: gelu, W3 partial dot, reduce over m16, combine wh via plog
#pragma unroll
    for (int j = 0; j < 2; ++j) {
        float part[16];
#pragma unroll
        for (int q = 0; q < 16; ++q) part[q] = 0.f;
#pragma unroll
        for (int tp = 0; tp < 4; ++tp)
#pragma unroll
            for (int th = 0; th < 4; ++th)
#pragma unroll
                for (int i = 0; i < 4; ++i)
                    part[tp * 4 + i] += w3v[th] * gelu_f(acc2[j][tp][th][i]);
#pragma unroll
        for (int mask = 1; mask <= 8; mask <<= 1)
#pragma unroll
            for (int q = 0; q < 16; ++q) part[q] += __shfl_xor(part[q], mask, 64);
        if (m16 == 0) {
#pragma unroll
            for (int tp = 0; tp < 4; ++tp)
#pragma unroll
                for (int i = 0; i < 4; ++i)
                    atomicAdd(&plog[j * 256 + p0 + tp * 16 + quad * 4 + i], part[tp * 4 + i]);
        }
    }
    __syncthreads();

    if (tid < 512) {
        int j = tid >> 8, p = tid & 255;
        int ml = ml0 + j;
        float pl;
        if (l_pad[ml] != 0) {
            pl = -20.f;
        } else {
            pl = plog[tid] + b3[0];
            if (__builtin_isnan(pl)) pl = 0.f;
            else if (__builtin_isinf(pl)) pl = pl > 0.f ? 20.f : -20.f;
            if (p_pad[b * LPP + p] != 0) pl = -20.f;
        }
        outPL[(size_t)ml * LPP + p] = pl;
        outPR[(size_t)ml * LPP + p] = sigmoid_f(pl);
    }
}

// ---------------------------------------------------------------------------
// Kernel 4: top-100 + softmax pool per batch. 3-pass radix (24-bit prefix,
// midpoint tie-merge). Pass 0 uses a 2-entry per-thread register bin cache:
// clustered logits aggregate in registers, collapsing same-bin LDS atomics.
// ---------------------------------------------------------------------------
__global__ __launch_bounds__(1024) void topk_k(const float* __restrict__ pl,
                                               float* __restrict__ out) {
    __shared__ int hist[16 * 256];
    __shared__ float redf[32];
    __shared__ unsigned bc_pref;
    __shared__ int bc_rem;
    __shared__ float bc_vmax;
    int b = blockIdx.x, tid = threadIdx.x;
    int wv = tid >> 6, lane = tid & 63;
    const float4* src = (const float4*)(pl + (size_t)b * 65536);

#pragma unroll
    for (int r = 0; r < 4; ++r) hist[tid + r * 1024] = 0;
    __syncthreads();

    float mx = -1e30f;
    int c20 = 0;
    const unsigned bin20 = okey(-20.f) >> 24;
    {
        int rep = wv * 256;
        unsigned cb0 = 0xffffffffu, cb1 = 0xffffffffu;
        int cc0 = 0, cc1 = 0;
        for (int j = 0; j < 16; ++j) {
            float4 t = src[tid + j * 1024];
#pragma unroll
            for (int c = 0; c < 4; ++c) {
                float v = (&t.x)[c];
                mx = fmaxf(mx, v);
                if (v == -20.f) { c20++; continue; }
                unsigned bin = okey(v) >> 24;
                if (bin & 1) {
                    if (bin == cb1) cc1++;
                    else {
                        if (cc1) atomicAdd(&hist[rep + cb1], cc1);
                        cb1 = bin; cc1 = 1;
                    }
                } else {
                    if (bin == cb0) cc0++;
                    else {
                        if (cc0) atomicAdd(&hist[rep + cb0], cc0);
                        cb0 = bin; cc0 = 1;
                    }
                }
            }
        }
        if (cc0) atomicAdd(&hist[rep + cb0], cc0);
        if (cc1) atomicAdd(&hist[rep + cb1], cc1);
        if (c20) atomicAdd(&hist[rep + bin20], c20);
    }
    for (int off = 32; off > 0; off >>= 1) mx = fmaxf(mx, __shfl_xor(mx, off, 64));
    if (lane == 0) redf[wv] = mx;
    __syncthreads();
    if (tid < 256) {
        int s = 0;
#pragma unroll
        for (int ww = 0; ww < 16; ++ww) s += hist[ww * 256 + tid];
        hist[tid] = s;
    }
    __syncthreads();
    if (tid == 0) {
        float m = redf[0];
        for (int i = 1; i < 16; ++i) m = fmaxf(m, redf[i]);
        bc_vmax = m;
        int cum = 0, chosen = 0, above = 0;
        for (int bin = 255; bin >= 0; --bin) {
            int c = hist[bin];
            if (cum + c >= 100) { chosen = bin; above = cum; break; }
            cum += c;
        }
        bc_pref = (unsigned)chosen;
        bc_rem = 100 - above;
    }
    __syncthreads();
    unsigned pref = bc_pref;
    int rem = bc_rem;

    for (int pass = 1; pass < 3; ++pass) {
        if (tid < 512) hist[tid] = 0;
        __syncthreads();
        int sh = 24 - 8 * pass;
        int rep = (wv & 1) * 256;
        for (int j = 0; j < 16; ++j) {
            float4 t = src[tid + j * 1024];
#pragma unroll
            for (int c = 0; c < 4; ++c) {
                unsigned u = okey((&t.x)[c]);
                if ((u >> (sh + 8)) == pref) atomicAdd(&hist[rep + ((u >> sh) & 255)], 1);
            }
        }
        __syncthreads();
        if (tid == 0) {
            int cum = 0, chosen = 0, above = 0;
            for (int bin = 255; bin >= 0; --bin) {
                int c = hist[bin] + hist[bin + 256];
                if (cum + c >= rem) { chosen = bin; above = cum; break; }
                cum += c;
            }
            bc_pref = (pref << 8) | (unsigned)chosen;
            bc_rem = rem - above;
        }
        __syncthreads();
        pref = bc_pref;
        rem = bc_rem;
        __syncthreads();
    }

    // pref = 24-bit prefix: include keys with (key>>8) > pref fully, plus rem
    // boundary elements at the bin's midpoint value (error << threshold).
    float vmax = bc_vmax;
    float s1 = 0.f, s2 = 0.f;
    for (int j = 0; j < 16; ++j) {
        float4 t = src[tid + j * 1024];
#pragma unroll
        for (int c = 0; c < 4; ++c) {
            float v = (&t.x)[c];
            if ((okey(v) >> 8) > pref) {
                float e = __expf(v - vmax);
                s1 += e;
                s2 += e * v;
            }
        }
    }
    for (int off = 32; off > 0; off >>= 1) {
        s1 += __shfl_xor(s1, off, 64);
        s2 += __shfl_xor(s2, off, 64);
    }
    if (lane == 0) { redf[wv] = s1; redf[16 + wv] = s2; }
    __syncthreads();
    if (tid == 0) {
        float t1 = 0.f, t2 = 0.f;
        for (int i = 0; i < 16; ++i) { t1 += redf[i]; t2 += redf[16 + i]; }
        unsigned key = (pref << 8) | 0x80u;
        unsigned bits = (key & 0x80000000u) ? (key & 0x7fffffffu) : ~key;
        float vT = __uint_as_float(bits);
        float e = __expf(vT - vmax);
        t1 += (float)rem * e;
        t2 += (float)rem * e * vT;
        out[b] = t2 / t1;
    }
}

// ---------------------------------------------------------------------------
extern "C" void kernel_launch(void* const* d_in, const int* in_sizes, int n_in,
                              void* d_out, int out_size, void* d_ws, size_t ws_size,
                              hipStream_t stream) {
    const float* l_tok = (const float*)d_in[0];
    const float* p_tok = (const float*)d_in[1];
    const int* l_pad = (const int*)d_in[2];
    const int* p_pad = (const int*)d_in[3];
    const float* Wl = (const float*)d_in[4];
    const float* bl = (const float*)d_in[5];
    const float* Wp = (const float*)d_in[6];
    const float* bp = (const float*)d_in[7];
    const float* W1 = (const float*)d_in[8];
    const float* b1 = (const float*)d_in[9];
    const float* W2 = (const float*)d_in[10];
    const float* b2 = (const float*)d_in[11];
    const float* W3 = (const float*)d_in[12];
    const float* b3 = (const float*)d_in[13];
    float* out = (float*)d_out;

    char* ws = (char*)d_ws;
    f16* proj = (f16*)ws;                                       // 2048*256 f16 = 1 MiB
    float* ABt = (float*)(ws + (size_t)2048 * 256 * 2);         // 128*2048 f32 = 1 MiB
    f16* w1g = (f16*)(ws + (size_t)2048 * 256 * 2 + (size_t)128 * 2048 * 4);  // 128 KiB
    f16* w2g = (f16*)((char*)w1g + (size_t)8192 * 16);          // 32 KiB

    cvt_w<<<40, 256, 0, stream>>>(W1, W2, w1g, w2g);
    prep_proj<<<dim3(32, 4), 256, 0, stream>>>(l_tok, p_tok, Wl, Wp, bl, bp, proj);
    prep_ab<<<dim3(32, 2), 256, 0, stream>>>(proj, W1, ABt);
    pair_main<<<dim3(LLL / 2, BB), 512, 0, stream>>>(proj, ABt, w1g, w2g, b1, b2, W3, b3,
                                                     l_pad, p_pad, out);
    topk_k<<<BB, 1024, 0, stream>>>(out + 4, out);
}

// Round 7
// 213.757 us; speedup vs baseline: 1.4652x; 1.0764x over previous
//
#include <hip/hip_runtime.h>

// Problem constants
#define BB 4
#define LLL 256
#define LPP 256
#define DDIM 256
#define HH 128

typedef _Float16 f16;
typedef f16 f16x8 __attribute__((ext_vector_type(8)));
typedef f16 f16x4 __attribute__((ext_vector_type(4)));
typedef float floatx4 __attribute__((ext_vector_type(4)));

// gelu(x) ~= x * sigmoid(1.702x); raw v_rcp_f32 instead of IEEE f32 division
// (div chain is ~10+ VALU insts; rcp is 1 transcendental, ~1 ulp error vs
// 0.4 abs tolerance).
__device__ __forceinline__ float gelu_f(float x) {
    return x * __builtin_amdgcn_rcpf(1.f + __expf(-1.702f * x));
}
__device__ __forceinline__ float sigmoid_f(float x) {
    return __builtin_amdgcn_rcpf(1.f + __expf(-x));
}
__device__ __forceinline__ f16x8 habs8(f16x8 v) {
    uint4 u = __builtin_bit_cast(uint4, v);
    u.x &= 0x7fff7fffu; u.y &= 0x7fff7fffu; u.z &= 0x7fff7fffu; u.w &= 0x7fff7fffu;
    return __builtin_bit_cast(f16x8, u);
}
__device__ __forceinline__ unsigned okey(float f) {
    unsigned u = __float_as_uint(f);
    return (u & 0x80000000u) ? ~u : (u | 0x80000000u);
}

// ---------------------------------------------------------------------------
// Kernel 1: projections. proj[m][e], m in [0,1024): l rows, [1024,2048): p rows
// ---------------------------------------------------------------------------
__global__ __launch_bounds__(256) void prep_proj(
    const float* __restrict__ l_tok, const float* __restrict__ p_tok,
    const float* __restrict__ Wl, const float* __restrict__ Wp,
    const float* __restrict__ bl, const float* __restrict__ bp,
    f16* __restrict__ proj) {
    __shared__ __align__(16) char sm[2 * 64 * 80];
    f16* As = (f16*)sm;
    f16* Bs = (f16*)(sm + 64 * 80);
    int tid = threadIdx.x;
    int m0 = blockIdx.x * 64, n0 = blockIdx.y * 64;
    bool isP = (m0 >= 1024);
    const float* Asrc = isP ? (p_tok + (size_t)(m0 - 1024) * DDIM) : (l_tok + (size_t)m0 * DDIM);
    const float* Wsrc = isP ? Wp : Wl;
    const float* bias = isP ? bp : bl;
    int row = tid >> 2, seg = tid & 3;
    int w = tid >> 6, lane = tid & 63;
    int m16 = lane & 15, quad = lane >> 4;
    int wm = w & 1, wn = w >> 1;
    floatx4 acc[2][2];
#pragma unroll
    for (int a = 0; a < 2; ++a)
#pragma unroll
        for (int c = 0; c < 2; ++c) acc[a][c] = (floatx4)0.f;
    for (int k0 = 0; k0 < DDIM; k0 += 32) {
        float4 f0 = *(const float4*)(Asrc + row * DDIM + k0 + seg * 8);
        float4 f1 = *(const float4*)(Asrc + row * DDIM + k0 + seg * 8 + 4);
        f16x8 av;
        av[0] = (f16)f0.x; av[1] = (f16)f0.y; av[2] = (f16)f0.z; av[3] = (f16)f0.w;
        av[4] = (f16)f1.x; av[5] = (f16)f1.y; av[6] = (f16)f1.z; av[7] = (f16)f1.w;
        *(f16x8*)(As + row * 40 + seg * 8) = av;
        float4 g0 = *(const float4*)(Wsrc + (n0 + row) * DDIM + k0 + seg * 8);
        float4 g1 = *(const float4*)(Wsrc + (n0 + row) * DDIM + k0 + seg * 8 + 4);
        f16x8 bv;
        bv[0] = (f16)g0.x; bv[1] = (f16)g0.y; bv[2] = (f16)g0.z; bv[3] = (f16)g0.w;
        bv[4] = (f16)g1.x; bv[5] = (f16)g1.y; bv[6] = (f16)g1.z; bv[7] = (f16)g1.w;
        *(f16x8*)(Bs + row * 40 + seg * 8) = bv;
        __syncthreads();
        f16x8 afr[2], bfr[2];
#pragma unroll
        for (int t = 0; t < 2; ++t)
            afr[t] = *(const f16x8*)(As + (wm * 32 + t * 16 + m16) * 40 + quad * 8);
#pragma unroll
        for (int t = 0; t < 2; ++t)
            bfr[t] = *(const f16x8*)(Bs + (wn * 32 + t * 16 + m16) * 40 + quad * 8);
#pragma unroll
        for (int a = 0; a < 2; ++a)
#pragma unroll
            for (int c = 0; c < 2; ++c)
                acc[a][c] = __builtin_amdgcn_mfma_f32_16x16x32_f16(afr[a], bfr[c], acc[a][c], 0, 0, 0);
        __syncthreads();
    }
#pragma unroll
    for (int c = 0; c < 2; ++c) {
        int col = n0 + wn * 32 + c * 16 + m16;
        float bv = bias[col];
#pragma unroll
        for (int a = 0; a < 2; ++a) {
            int rbase = m0 + wm * 32 + a * 16 + quad * 4;
#pragma unroll
            for (int i = 0; i < 4; ++i)
                proj[(size_t)(rbase + i) * DDIM + col] = (f16)(acc[a][c][i] + bv);
        }
    }
}

// ---------------------------------------------------------------------------
// Kernel 2: A/Bp transposed: ABt[h][m] (fp32 [128][2048]).
// Blocks x>=32 instead build fragment-ordered w1g/w2g (fused former cvt_w):
//   w1g chunk c: c = ((ds*2+cd)*8+thg)*64 + quad*16 + m16
//     holds W1[h=thg*16+m16][512 + cd*256 + ds*32 + quad*8 + j]
//   w2g chunk c: c = (ks*8+tg)*64 + quad*16 + m16
//     holds W2[g=tg*16+m16][h = j*16 + ks*4 + quad]  (pi: k'=(h&15)*8+(h>>4))
// ---------------------------------------------------------------------------
__global__ __launch_bounds__(256) void prep_ab(
    const f16* __restrict__ proj, const float* __restrict__ W1,
    const float* __restrict__ W2, float* __restrict__ ABt,
    f16* __restrict__ w1g, f16* __restrict__ w2g) {
    int tid = threadIdx.x;
    if (blockIdx.x >= 32) {
        int idx = ((blockIdx.x - 32) * 2 + blockIdx.y) * 256 + tid;
        if (idx < 8192) {
            int m16 = idx & 15, quad = (idx >> 4) & 3, th = (idx >> 6) & 7;
            int cd = (idx >> 9) & 1, ds = idx >> 10;
            int h = th * 16 + m16;
            const float* src = W1 + (size_t)h * 1024 + 512 + cd * 256 + ds * 32 + quad * 8;
            f16x8 v;
#pragma unroll
            for (int j = 0; j < 8; ++j) v[j] = (f16)src[j];
            *(f16x8*)(w1g + (size_t)idx * 8) = v;
        } else if (idx < 8192 + 2048) {
            int c = idx - 8192;
            int m16 = c & 15, quad = (c >> 4) & 3, tg = (c >> 6) & 7, ks = c >> 9;
            int g = tg * 16 + m16;
            f16x8 v;
#pragma unroll
            for (int j = 0; j < 8; ++j) v[j] = (f16)W2[g * HH + j * 16 + ks * 4 + quad];
            *(f16x8*)(w2g + (size_t)c * 8) = v;
        }
        return;
    }
    __shared__ __align__(16) char sm[2 * 64 * 80];
    f16* As = (f16*)sm;
    f16* Bs = (f16*)(sm + 64 * 80);
    int m0 = blockIdx.x * 64, n0 = blockIdx.y * 64;
    bool isP = (m0 >= 1024);
    int koff = isP ? 256 : 0;
    int row = tid >> 2, seg = tid & 3;
    int w = tid >> 6, lane = tid & 63;
    int m16 = lane & 15, quad = lane >> 4;
    int wm = w & 1, wn = w >> 1;
    floatx4 acc[2][2];
#pragma unroll
    for (int a = 0; a < 2; ++a)
#pragma unroll
        for (int c = 0; c < 2; ++c) acc[a][c] = (floatx4)0.f;
    for (int k0 = 0; k0 < DDIM; k0 += 32) {
        f16x8 av = *(const f16x8*)(proj + (size_t)(m0 + row) * DDIM + k0 + seg * 8);
        *(f16x8*)(As + row * 40 + seg * 8) = av;
        float4 g0 = *(const float4*)(W1 + (size_t)(n0 + row) * 1024 + koff + k0 + seg * 8);
        float4 g1 = *(const float4*)(W1 + (size_t)(n0 + row) * 1024 + koff + k0 + seg * 8 + 4);
        f16x8 bv;
        bv[0] = (f16)g0.x; bv[1] = (f16)g0.y; bv[2] = (f16)g0.z; bv[3] = (f16)g0.w;
        bv[4] = (f16)g1.x; bv[5] = (f16)g1.y; bv[6] = (f16)g1.z; bv[7] = (f16)g1.w;
        *(f16x8*)(Bs + row * 40 + seg * 8) = bv;
        __syncthreads();
        f16x8 afr[2], bfr[2];
#pragma unroll
        for (int t = 0; t < 2; ++t)
            afr[t] = *(const f16x8*)(As + (wm * 32 + t * 16 + m16) * 40 + quad * 8);
#pragma unroll
        for (int t = 0; t < 2; ++t)
            bfr[t] = *(const f16x8*)(Bs + (wn * 32 + t * 16 + m16) * 40 + quad * 8);
#pragma unroll
        for (int a = 0; a < 2; ++a)
#pragma unroll
            for (int c = 0; c < 2; ++c)
                acc[a][c] = __builtin_amdgcn_mfma_f32_16x16x32_f16(afr[a], bfr[c], acc[a][c], 0, 0, 0);
        __syncthreads();
    }
#pragma unroll
    for (int c = 0; c < 2; ++c) {
        int col = n0 + wn * 32 + c * 16 + m16;
#pragma unroll
        for (int a = 0; a < 2; ++a) {
            int rbase = m0 + wm * 32 + a * 16 + quad * 4;
#pragma unroll
            for (int i = 0; i < 4; ++i)
                ABt[(size_t)col * 2048 + rbase + i] = acc[a][c][i];
        }
    }
}

// ---------------------------------------------------------------------------
// Kernel 3: main pair kernel. 512 threads = 8 waves, block = TWO l-rows.
// Wave w: wp = w&3 (64 p), wh = w>>2 (64 h); each wave computes BOTH l-rows
// (acc[2][4][4] = 128 AGPR) so pv / W1-frag staging is amortized over 128
// MFMA per ds-step. K-loop barrier-free, register double-buffer on pv/lv.
// LDS: W1 frag-ordered 128 KB (staged once), overlaid after K-loop by
// h1' (2 x 256 x 272 B, conflict-free stride); plog 2 KB. 1 block/CU.
// ---------------------------------------------------------------------------
#define H1_STRIDE 272
#define SM_PLOG 139264
#define SM_TOTAL 141312

__global__ __launch_bounds__(512, 2) void pair_main(
    const f16* __restrict__ proj, const float* __restrict__ ABt,
    const f16* __restrict__ w1g, const f16* __restrict__ w2g,
    const float* __restrict__ b1, const float* __restrict__ b2,
    const float* __restrict__ W3, const float* __restrict__ b3,
    const int* __restrict__ l_pad, const int* __restrict__ p_pad,
    float* __restrict__ out) {
    __shared__ __align__(16) char sm[SM_TOTAL];
    int tid = threadIdx.x;
    int lane = tid & 63, w = tid >> 6;
    int m16 = lane & 15, quad = lane >> 4;
    int wp = w & 3, wh = w >> 2;
    int p0 = wp * 64, h0 = wh * 64;
    int b = blockIdx.y;
    int l0 = blockIdx.x * 2;
    int ml0 = b * LLL + l0;
    float* outPL = out + 4;
    float* outPR = out + 4 + BB * LLL * LPP;

    bool pad0 = (l_pad[ml0] != 0), pad1 = (l_pad[ml0 + 1] != 0);
    if (pad0 && pad1) {  // block-uniform fast path
        float pr = sigmoid_f(-20.f);
        if (tid < 512) {
            int j = tid >> 8, p = tid & 255;
            outPL[(size_t)(ml0 + j) * LPP + p] = -20.f;
            outPR[(size_t)(ml0 + j) * LPP + p] = pr;
        }
        return;
    }

    float* plog = (float*)(sm + SM_PLOG);

    // stage fragment-ordered W1c|W1d into LDS (linear 128 KB copy)
#pragma unroll
    for (int r = 0; r < 16; ++r) {
        int c = tid + r * 512;
        *(f16x8*)(sm + c * 16) = *(const f16x8*)(w1g + (size_t)c * 8);
    }
    if (tid < 512) plog[tid] = 0.f;

    // accumulator init: A[l_j,h] + b1[h] + Bp[p,h]  (Bp shared across j)
    floatx4 acc[2][4][4];
    {
        float av[2][4];
#pragma unroll
        for (int th = 0; th < 4; ++th) {
            int hh = h0 + th * 16 + m16;
            float base = b1[hh];
            av[0][th] = ABt[(size_t)hh * 2048 + ml0] + base;
            av[1][th] = ABt[(size_t)hh * 2048 + ml0 + 1] + base;
        }
#pragma unroll
        for (int tp = 0; tp < 4; ++tp) {
            int rp = p0 + tp * 16 + quad * 4;
#pragma unroll
            for (int th = 0; th < 4; ++th) {
                int hh = h0 + th * 16 + m16;
                floatx4 bp4 = *(const floatx4*)(ABt + (size_t)hh * 2048 + 1024 + b * LPP + rp);
#pragma unroll
                for (int j = 0; j < 2; ++j) {
                    floatx4 a;
#pragma unroll
                    for (int i = 0; i < 4; ++i) a[i] = bp4[i] + av[j][th];
                    acc[j][tp][th] = a;
                }
            }
        }
    }
    __syncthreads();

    // GEMM1 K-loop: barrier-free, 128 MFMA per ds, pv/lv double-buffered
    {
        const f16* Lr0 = proj + (size_t)ml0 * DDIM + quad * 8;
        const f16* Lr1 = Lr0 + DDIM;
        const f16* Prl[4];
#pragma unroll
        for (int tp = 0; tp < 4; ++tp)
            Prl[tp] = proj + (size_t)(1024 + b * LPP + p0 + tp * 16 + m16) * DDIM + quad * 8;

        f16x8 lv0 = *(const f16x8*)(Lr0);
        f16x8 lv1 = *(const f16x8*)(Lr1);
        f16x8 pv[4];
#pragma unroll
        for (int tp = 0; tp < 4; ++tp) pv[tp] = *(const f16x8*)(Prl[tp]);

        for (int ds = 0; ds < 8; ++ds) {
            f16x8 nlv0, nlv1, npv[4];
            if (ds < 7) {
                nlv0 = *(const f16x8*)(Lr0 + (ds + 1) * 32);
                nlv1 = *(const f16x8*)(Lr1 + (ds + 1) * 32);
#pragma unroll
                for (int tp = 0; tp < 4; ++tp)
                    npv[tp] = *(const f16x8*)(Prl[tp] + (ds + 1) * 32);
            }
            const char* wb = sm + (size_t)(ds * 2) * 8192 + (wh * 4) * 1024 + quad * 256 + m16 * 16;
            // c-half: x = l*p vs W1c
            {
                f16x8 x[2][4];
#pragma unroll
                for (int tp = 0; tp < 4; ++tp) {
                    x[0][tp] = lv0 * pv[tp];
                    x[1][tp] = lv1 * pv[tp];
                }
#pragma unroll
                for (int th = 0; th < 4; ++th) {
                    f16x8 bf = *(const f16x8*)(wb + th * 1024);
#pragma unroll
                    for (int j = 0; j < 2; ++j)
#pragma unroll
                        for (int tp = 0; tp < 4; ++tp)
                            acc[j][tp][th] = __builtin_amdgcn_mfma_f32_16x16x32_f16(x[j][tp], bf, acc[j][tp][th], 0, 0, 0);
                }
            }
            // d-half: x = |l-p| vs W1d
            {
                f16x8 x[2][4];
#pragma unroll
                for (int tp = 0; tp < 4; ++tp) {
                    x[0][tp] = habs8(lv0 - pv[tp]);
                    x[1][tp] = habs8(lv1 - pv[tp]);
                }
#pragma unroll
                for (int th = 0; th < 4; ++th) {
                    f16x8 bf = *(const f16x8*)(wb + 8192 + th * 1024);
#pragma unroll
                    for (int j = 0; j < 2; ++j)
#pragma unroll
                        for (int tp = 0; tp < 4; ++tp)
                            acc[j][tp][th] = __builtin_amdgcn_mfma_f32_16x16x32_f16(x[j][tp], bf, acc[j][tp][th], 0, 0, 0);
                }
            }
            lv0 = nlv0; lv1 = nlv1;
#pragma unroll
            for (int tp = 0; tp < 4; ++tp) pv[tp] = npv[tp];
        }
    }
    __syncthreads();  // all waves done reading W1 LDS before h1 overlay

    // h1' (pi-space) overlay: k' = m16*8 + wh*4 + th  -> byte m16*16 + wh*8
#pragma unroll
    for (int j = 0; j < 2; ++j) {
        char* h1s = sm + j * (256 * H1_STRIDE);
#pragma unroll
        for (int tp = 0; tp < 4; ++tp) {
#pragma unroll
            for (int i = 0; i < 4; ++i) {
                f16x4 hv;
#pragma unroll
                for (int th = 0; th < 4; ++th) hv[th] = (f16)gelu_f(acc[j][tp][th][i]);
                int p = p0 + tp * 16 + quad * 4 + i;
                *(f16x4*)(h1s + p * H1_STRIDE + m16 * 16 + wh * 8) = hv;
            }
        }
    }
    __syncthreads();

    // GEMM2: wave 2l x 64p x 64g, K'=128 (W2 pre-permuted in w2g, L1-hot)
    float b2v[4], w3v[4];
#pragma unroll
    for (int th = 0; th < 4; ++th) {
        int g = h0 + th * 16 + m16;
        b2v[th] = b2[g];
        w3v[th] = W3[g];
    }
    floatx4 acc2[2][4][4];
#pragma unroll
    for (int j = 0; j < 2; ++j)
#pragma unroll
        for (int tp = 0; tp < 4; ++tp)
#pragma unroll
            for (int th = 0; th < 4; ++th) {
                floatx4 a;
                a[0] = a[1] = a[2] = a[3] = b2v[th];
                acc2[j][tp][th] = a;
            }
#pragma unroll
    for (int ks = 0; ks < 4; ++ks) {
        f16x8 af[2][4];
#pragma unroll
        for (int j = 0; j < 2; ++j)
#pragma unroll
            for (int tp = 0; tp < 4; ++tp)
                af[j][tp] = *(const f16x8*)(sm + j * (256 * H1_STRIDE) +
                                            (p0 + tp * 16 + m16) * H1_STRIDE + ks * 64 + quad * 16);
#pragma unroll
        for (int th = 0; th < 4; ++th) {
            f16x8 bf = *(const f16x8*)(w2g + (size_t)(((ks * 8 + wh * 4 + th) * 4 + quad) * 16 + m16) * 8);
#pragma unroll
            for (int j = 0; j < 2; ++j)
#pragma unroll
                for (int tp = 0; tp < 4; ++tp)
                    acc2[j][tp][th] = __builtin_amdgcn_mfma_f32_16x16x32_f16(af[j][tp], bf, acc2[j][tp][th], 0, 0, 0);
        }
    }

    // epilogue: gelu, W3 partial dot, reduce over m16, combine wh via plog
#pragma unroll
    for (int j = 0; j < 2; ++j) {
        float part[16];
#pragma unroll
        for (int q = 0; q < 16; ++q) part[q] = 0.f;
#pragma unroll
        for (int tp = 0; tp < 4; ++tp)
#pragma unroll
            for (int th = 0; th < 4; ++th)
#pragma unroll
                for (int i = 0; i < 4; ++i)
                    part[tp * 4 + i] += w3v[th] * gelu_f(acc2[j][tp][th][i]);
#pragma unroll
        for (int mask = 1; mask <= 8; mask <<= 1)
#pragma unroll
            for (int q = 0; q < 16; ++q) part[q] += __shfl_xor(part[q], mask, 64);
        if (m16 == 0) {
#pragma unroll
            for (int tp = 0; tp < 4; ++tp)
#pragma unroll
                for (int i = 0; i < 4; ++i)
                    atomicAdd(&plog[j * 256 + p0 + tp * 16 + quad * 4 + i], part[tp * 4 + i]);
        }
    }
    __syncthreads();

    if (tid < 512) {
        int j = tid >> 8, p = tid & 255;
        int ml = ml0 + j;
        float pl;
        if (l_pad[ml] != 0) {
            pl = -20.f;
        } else {
            pl = plog[tid] + b3[0];
            if (__builtin_isnan(pl)) pl = 0.f;
            else if (__builtin_isinf(pl)) pl = pl > 0.f ? 20.f : -20.f;
            if (p_pad[b * LPP + p] != 0) pl = -20.f;
        }
        outPL[(size_t)ml * LPP + p] = pl;
        outPR[(size_t)ml * LPP + p] = sigmoid_f(pl);
    }
}

// ---------------------------------------------------------------------------
// Kernel 4: top-100 + softmax pool per batch. 3-pass radix (24-bit prefix,
// midpoint tie-merge). Pass 0 uses a 2-entry per-thread register bin cache.
// ---------------------------------------------------------------------------
__global__ __launch_bounds__(1024) void topk_k(const float* __restrict__ pl,
                                               float* __restrict__ out) {
    __shared__ int hist[16 * 256];
    __shared__ float redf[32];
    __shared__ unsigned bc_pref;
    __shared__ int bc_rem;
    __shared__ float bc_vmax;
    int b = blockIdx.x, tid = threadIdx.x;
    int wv = tid >> 6, lane = tid & 63;
    const float4* src = (const float4*)(pl + (size_t)b * 65536);

#pragma unroll
    for (int r = 0; r < 4; ++r) hist[tid + r * 1024] = 0;
    __syncthreads();

    float mx = -1e30f;
    int c20 = 0;
    const unsigned bin20 = okey(-20.f) >> 24;
    {
        int rep = wv * 256;
        unsigned cb0 = 0xffffffffu, cb1 = 0xffffffffu;
        int cc0 = 0, cc1 = 0;
        for (int j = 0; j < 16; ++j) {
            float4 t = src[tid + j * 1024];
#pragma unroll
            for (int c = 0; c < 4; ++c) {
                float v = (&t.x)[c];
                mx = fmaxf(mx, v);
                if (v == -20.f) { c20++; continue; }
                unsigned bin = okey(v) >> 24;
                if (bin & 1) {
                    if (bin == cb1) cc1++;
                    else {
                        if (cc1) atomicAdd(&hist[rep + cb1], cc1);
                        cb1 = bin; cc1 = 1;
                    }
                } else {
                    if (bin == cb0) cc0++;
                    else {
                        if (cc0) atomicAdd(&hist[rep + cb0], cc0);
                        cb0 = bin; cc0 = 1;
                    }
                }
            }
        }
        if (cc0) atomicAdd(&hist[rep + cb0], cc0);
        if (cc1) atomicAdd(&hist[rep + cb1], cc1);
        if (c20) atomicAdd(&hist[rep + bin20], c20);
    }
    for (int off = 32; off > 0; off >>= 1) mx = fmaxf(mx, __shfl_xor(mx, off, 64));
    if (lane == 0) redf[wv] = mx;
    __syncthreads();
    if (tid < 256) {
        int s = 0;
#pragma unroll
        for (int ww = 0; ww < 16; ++ww) s += hist[ww * 256 + tid];
        hist[tid] = s;
    }
    __syncthreads();
    if (tid == 0) {
        float m = redf[0];
        for (int i = 1; i < 16; ++i) m = fmaxf(m, redf[i]);
        bc_vmax = m;
        int cum = 0, chosen = 0, above = 0;
        for (int bin = 255; bin >= 0; --bin) {
            int c = hist[bin];
            if (cum + c >= 100) { chosen = bin; above = cum; break; }
            cum += c;
        }
        bc_pref = (unsigned)chosen;
        bc_rem = 100 - above;
    }
    __syncthreads();
    unsigned pref = bc_pref;
    int rem = bc_rem;

    for (int pass = 1; pass < 3; ++pass) {
        if (tid < 512) hist[tid] = 0;
        __syncthreads();
        int sh = 24 - 8 * pass;
        int rep = (wv & 1) * 256;
        for (int j = 0; j < 16; ++j) {
            float4 t = src[tid + j * 1024];
#pragma unroll
            for (int c = 0; c < 4; ++c) {
                unsigned u = okey((&t.x)[c]);
                if ((u >> (sh + 8)) == pref) atomicAdd(&hist[rep + ((u >> sh) & 255)], 1);
            }
        }
        __syncthreads();
        if (tid == 0) {
            int cum = 0, chosen = 0, above = 0;
            for (int bin = 255; bin >= 0; --bin) {
                int c = hist[bin] + hist[bin + 256];
                if (cum + c >= rem) { chosen = bin; above = cum; break; }
                cum += c;
            }
            bc_pref = (pref << 8) | (unsigned)chosen;
            bc_rem = rem - above;
        }
        __syncthreads();
        pref = bc_pref;
        rem = bc_rem;
        __syncthreads();
    }

    // pref = 24-bit prefix: include keys with (key>>8) > pref fully, plus rem
    // boundary elements at the bin's midpoint value (error << threshold).
    float vmax = bc_vmax;
    float s1 = 0.f, s2 = 0.f;
    for (int j = 0; j < 16; ++j) {
        float4 t = src[tid + j * 1024];
#pragma unroll
        for (int c = 0; c < 4; ++c) {
            float v = (&t.x)[c];
            if ((okey(v) >> 8) > pref) {
                float e = __expf(v - vmax);
                s1 += e;
                s2 += e * v;
            }
        }
    }
    for (int off = 32; off > 0; off >>= 1) {
        s1 += __shfl_xor(s1, off, 64);
        s2 += __shfl_xor(s2, off, 64);
    }
    if (lane == 0) { redf[wv] = s1; redf[16 + wv] = s2; }
    __syncthreads();
    if (tid == 0) {
        float t1 = 0.f, t2 = 0.f;
        for (int i = 0; i < 16; ++i) { t1 += redf[i]; t2 += redf[16 + i]; }
        unsigned key = (pref << 8) | 0x80u;
        unsigned bits = (key & 0x80000000u) ? (key & 0x7fffffffu) : ~key;
        float vT = __uint_as_float(bits);
        float e = __expf(vT - vmax);
        t1 += (float)rem * e;
        t2 += (float)rem * e * vT;
        out[b] = t2 / t1;
    }
}

// ---------------------------------------------------------------------------
extern "C" void kernel_launch(void* const* d_in, const int* in_sizes, int n_in,
                              void* d_out, int out_size, void* d_ws, size_t ws_size,
                              hipStream_t stream) {
    const float* l_tok = (const float*)d_in[0];
    const float* p_tok = (const float*)d_in[1];
    const int* l_pad = (const int*)d_in[2];
    const int* p_pad = (const int*)d_in[3];
    const float* Wl = (const float*)d_in[4];
    const float* bl = (const float*)d_in[5];
    const float* Wp = (const float*)d_in[6];
    const float* bp = (const float*)d_in[7];
    const float* W1 = (const float*)d_in[8];
    const float* b1 = (const float*)d_in[9];
    const float* W2 = (const float*)d_in[10];
    const float* b2 = (const float*)d_in[11];
    const float* W3 = (const float*)d_in[12];
    const float* b3 = (const float*)d_in[13];
    float* out = (float*)d_out;

    char* ws = (char*)d_ws;
    f16* proj = (f16*)ws;                                       // 2048*256 f16 = 1 MiB
    float* ABt = (float*)(ws + (size_t)2048 * 256 * 2);         // 128*2048 f32 = 1 MiB
    f16* w1g = (f16*)(ws + (size_t)2048 * 256 * 2 + (size_t)128 * 2048 * 4);  // 128 KiB
    f16* w2g = (f16*)((char*)w1g + (size_t)8192 * 16);          // 32 KiB

    prep_proj<<<dim3(32, 4), 256, 0, stream>>>(l_tok, p_tok, Wl, Wp, bl, bp, proj);
    prep_ab<<<dim3(52, 2), 256, 0, stream>>>(proj, W1, W2, ABt, w1g, w2g);
    pair_main<<<dim3(LLL / 2, BB), 512, 0, stream>>>(proj, ABt, w1g, w2g, b1, b2, W3, b3,
                                                     l_pad, p_pad, out);
    topk_k<<<BB, 1024, 0, stream>>>(out + 4, out);
}

// Round 8
// 178.060 us; speedup vs baseline: 1.7590x; 1.2005x over previous
//
#include <hip/hip_runtime.h>

// Problem constants
#define BB 4
#define LLL 256
#define LPP 256
#define DDIM 256
#define HH 128

typedef _Float16 f16;
typedef f16 f16x8 __attribute__((ext_vector_type(8)));
typedef f16 f16x4 __attribute__((ext_vector_type(4)));
typedef float floatx4 __attribute__((ext_vector_type(4)));

// gelu(x) ~= x * sigmoid(1.702x); raw v_rcp_f32 instead of IEEE f32 division.
__device__ __forceinline__ float gelu_f(float x) {
    return x * __builtin_amdgcn_rcpf(1.f + __expf(-1.702f * x));
}
__device__ __forceinline__ float sigmoid_f(float x) {
    return __builtin_amdgcn_rcpf(1.f + __expf(-x));
}
__device__ __forceinline__ f16x8 habs8(f16x8 v) {
    uint4 u = __builtin_bit_cast(uint4, v);
    u.x &= 0x7fff7fffu; u.y &= 0x7fff7fffu; u.z &= 0x7fff7fffu; u.w &= 0x7fff7fffu;
    return __builtin_bit_cast(f16x8, u);
}
__device__ __forceinline__ unsigned okey(float f) {
    unsigned u = __float_as_uint(f);
    return (u & 0x80000000u) ? ~u : (u | 0x80000000u);
}

// ---------------------------------------------------------------------------
// Kernel 1: projections. proj[m][e], m in [0,1024): l rows, [1024,2048): p rows
// ---------------------------------------------------------------------------
__global__ __launch_bounds__(256) void prep_proj(
    const float* __restrict__ l_tok, const float* __restrict__ p_tok,
    const float* __restrict__ Wl, const float* __restrict__ Wp,
    const float* __restrict__ bl, const float* __restrict__ bp,
    f16* __restrict__ proj) {
    __shared__ __align__(16) char sm[2 * 64 * 80];
    f16* As = (f16*)sm;
    f16* Bs = (f16*)(sm + 64 * 80);
    int tid = threadIdx.x;
    int m0 = blockIdx.x * 64, n0 = blockIdx.y * 64;
    bool isP = (m0 >= 1024);
    const float* Asrc = isP ? (p_tok + (size_t)(m0 - 1024) * DDIM) : (l_tok + (size_t)m0 * DDIM);
    const float* Wsrc = isP ? Wp : Wl;
    const float* bias = isP ? bp : bl;
    int row = tid >> 2, seg = tid & 3;
    int w = tid >> 6, lane = tid & 63;
    int m16 = lane & 15, quad = lane >> 4;
    int wm = w & 1, wn = w >> 1;
    floatx4 acc[2][2];
#pragma unroll
    for (int a = 0; a < 2; ++a)
#pragma unroll
        for (int c = 0; c < 2; ++c) acc[a][c] = (floatx4)0.f;
    for (int k0 = 0; k0 < DDIM; k0 += 32) {
        float4 f0 = *(const float4*)(Asrc + row * DDIM + k0 + seg * 8);
        float4 f1 = *(const float4*)(Asrc + row * DDIM + k0 + seg * 8 + 4);
        f16x8 av;
        av[0] = (f16)f0.x; av[1] = (f16)f0.y; av[2] = (f16)f0.z; av[3] = (f16)f0.w;
        av[4] = (f16)f1.x; av[5] = (f16)f1.y; av[6] = (f16)f1.z; av[7] = (f16)f1.w;
        *(f16x8*)(As + row * 40 + seg * 8) = av;
        float4 g0 = *(const float4*)(Wsrc + (n0 + row) * DDIM + k0 + seg * 8);
        float4 g1 = *(const float4*)(Wsrc + (n0 + row) * DDIM + k0 + seg * 8 + 4);
        f16x8 bv;
        bv[0] = (f16)g0.x; bv[1] = (f16)g0.y; bv[2] = (f16)g0.z; bv[3] = (f16)g0.w;
        bv[4] = (f16)g1.x; bv[5] = (f16)g1.y; bv[6] = (f16)g1.z; bv[7] = (f16)g1.w;
        *(f16x8*)(Bs + row * 40 + seg * 8) = bv;
        __syncthreads();
        f16x8 afr[2], bfr[2];
#pragma unroll
        for (int t = 0; t < 2; ++t)
            afr[t] = *(const f16x8*)(As + (wm * 32 + t * 16 + m16) * 40 + quad * 8);
#pragma unroll
        for (int t = 0; t < 2; ++t)
            bfr[t] = *(const f16x8*)(Bs + (wn * 32 + t * 16 + m16) * 40 + quad * 8);
#pragma unroll
        for (int a = 0; a < 2; ++a)
#pragma unroll
            for (int c = 0; c < 2; ++c)
                acc[a][c] = __builtin_amdgcn_mfma_f32_16x16x32_f16(afr[a], bfr[c], acc[a][c], 0, 0, 0);
        __syncthreads();
    }
#pragma unroll
    for (int c = 0; c < 2; ++c) {
        int col = n0 + wn * 32 + c * 16 + m16;
        float bv = bias[col];
#pragma unroll
        for (int a = 0; a < 2; ++a) {
            int rbase = m0 + wm * 32 + a * 16 + quad * 4;
#pragma unroll
            for (int i = 0; i < 4; ++i)
                proj[(size_t)(rbase + i) * DDIM + col] = (f16)(acc[a][c][i] + bv);
        }
    }
}

// ---------------------------------------------------------------------------
// Kernel 2: A/Bp transposed: ABt[h][m] (fp32 [128][2048]).
// Blocks x>=32 build fragment-ordered w1g/w2g (fused weight repack).
// ---------------------------------------------------------------------------
__global__ __launch_bounds__(256) void prep_ab(
    const f16* __restrict__ proj, const float* __restrict__ W1,
    const float* __restrict__ W2, float* __restrict__ ABt,
    f16* __restrict__ w1g, f16* __restrict__ w2g) {
    int tid = threadIdx.x;
    if (blockIdx.x >= 32) {
        int idx = ((blockIdx.x - 32) * 2 + blockIdx.y) * 256 + tid;
        if (idx < 8192) {
            int m16 = idx & 15, quad = (idx >> 4) & 3, th = (idx >> 6) & 7;
            int cd = (idx >> 9) & 1, ds = idx >> 10;
            int h = th * 16 + m16;
            const float* src = W1 + (size_t)h * 1024 + 512 + cd * 256 + ds * 32 + quad * 8;
            f16x8 v;
#pragma unroll
            for (int j = 0; j < 8; ++j) v[j] = (f16)src[j];
            *(f16x8*)(w1g + (size_t)idx * 8) = v;
        } else if (idx < 8192 + 2048) {
            int c = idx - 8192;
            int m16 = c & 15, quad = (c >> 4) & 3, tg = (c >> 6) & 7, ks = c >> 9;
            int g = tg * 16 + m16;
            f16x8 v;
#pragma unroll
            for (int j = 0; j < 8; ++j) v[j] = (f16)W2[g * HH + j * 16 + ks * 4 + quad];
            *(f16x8*)(w2g + (size_t)c * 8) = v;
        }
        return;
    }
    __shared__ __align__(16) char sm[2 * 64 * 80];
    f16* As = (f16*)sm;
    f16* Bs = (f16*)(sm + 64 * 80);
    int m0 = blockIdx.x * 64, n0 = blockIdx.y * 64;
    bool isP = (m0 >= 1024);
    int koff = isP ? 256 : 0;
    int row = tid >> 2, seg = tid & 3;
    int w = tid >> 6, lane = tid & 63;
    int m16 = lane & 15, quad = lane >> 4;
    int wm = w & 1, wn = w >> 1;
    floatx4 acc[2][2];
#pragma unroll
    for (int a = 0; a < 2; ++a)
#pragma unroll
        for (int c = 0; c < 2; ++c) acc[a][c] = (floatx4)0.f;
    for (int k0 = 0; k0 < DDIM; k0 += 32) {
        f16x8 av = *(const f16x8*)(proj + (size_t)(m0 + row) * DDIM + k0 + seg * 8);
        *(f16x8*)(As + row * 40 + seg * 8) = av;
        float4 g0 = *(const float4*)(W1 + (size_t)(n0 + row) * 1024 + koff + k0 + seg * 8);
        float4 g1 = *(const float4*)(W1 + (size_t)(n0 + row) * 1024 + koff + k0 + seg * 8 + 4);
        f16x8 bv;
        bv[0] = (f16)g0.x; bv[1] = (f16)g0.y; bv[2] = (f16)g0.z; bv[3] = (f16)g0.w;
        bv[4] = (f16)g1.x; bv[5] = (f16)g1.y; bv[6] = (f16)g1.z; bv[7] = (f16)g1.w;
        *(f16x8*)(Bs + row * 40 + seg * 8) = bv;
        __syncthreads();
        f16x8 afr[2], bfr[2];
#pragma unroll
        for (int t = 0; t < 2; ++t)
            afr[t] = *(const f16x8*)(As + (wm * 32 + t * 16 + m16) * 40 + quad * 8);
#pragma unroll
        for (int t = 0; t < 2; ++t)
            bfr[t] = *(const f16x8*)(Bs + (wn * 32 + t * 16 + m16) * 40 + quad * 8);
#pragma unroll
        for (int a = 0; a < 2; ++a)
#pragma unroll
            for (int c = 0; c < 2; ++c)
                acc[a][c] = __builtin_amdgcn_mfma_f32_16x16x32_f16(afr[a], bfr[c], acc[a][c], 0, 0, 0);
        __syncthreads();
    }
#pragma unroll
    for (int c = 0; c < 2; ++c) {
        int col = n0 + wn * 32 + c * 16 + m16;
#pragma unroll
        for (int a = 0; a < 2; ++a) {
            int rbase = m0 + wm * 32 + a * 16 + quad * 4;
#pragma unroll
            for (int i = 0; i < 4; ++i)
                ABt[(size_t)col * 2048 + rbase + i] = acc[a][c][i];
        }
    }
}

// ---------------------------------------------------------------------------
// Kernel 3: main pair kernel (unchanged from R7 passing state).
// ---------------------------------------------------------------------------
#define H1_STRIDE 272
#define SM_PLOG 139264
#define SM_TOTAL 141312

__global__ __launch_bounds__(512, 2) void pair_main(
    const f16* __restrict__ proj, const float* __restrict__ ABt,
    const f16* __restrict__ w1g, const f16* __restrict__ w2g,
    const float* __restrict__ b1, const float* __restrict__ b2,
    const float* __restrict__ W3, const float* __restrict__ b3,
    const int* __restrict__ l_pad, const int* __restrict__ p_pad,
    float* __restrict__ out) {
    __shared__ __align__(16) char sm[SM_TOTAL];
    int tid = threadIdx.x;
    int lane = tid & 63, w = tid >> 6;
    int m16 = lane & 15, quad = lane >> 4;
    int wp = w & 3, wh = w >> 2;
    int p0 = wp * 64, h0 = wh * 64;
    int b = blockIdx.y;
    int l0 = blockIdx.x * 2;
    int ml0 = b * LLL + l0;
    float* outPL = out + 4;
    float* outPR = out + 4 + BB * LLL * LPP;

    bool pad0 = (l_pad[ml0] != 0), pad1 = (l_pad[ml0 + 1] != 0);
    if (pad0 && pad1) {
        float pr = sigmoid_f(-20.f);
        if (tid < 512) {
            int j = tid >> 8, p = tid & 255;
            outPL[(size_t)(ml0 + j) * LPP + p] = -20.f;
            outPR[(size_t)(ml0 + j) * LPP + p] = pr;
        }
        return;
    }

    float* plog = (float*)(sm + SM_PLOG);

#pragma unroll
    for (int r = 0; r < 16; ++r) {
        int c = tid + r * 512;
        *(f16x8*)(sm + c * 16) = *(const f16x8*)(w1g + (size_t)c * 8);
    }
    if (tid < 512) plog[tid] = 0.f;

    floatx4 acc[2][4][4];
    {
        float av[2][4];
#pragma unroll
        for (int th = 0; th < 4; ++th) {
            int hh = h0 + th * 16 + m16;
            float base = b1[hh];
            av[0][th] = ABt[(size_t)hh * 2048 + ml0] + base;
            av[1][th] = ABt[(size_t)hh * 2048 + ml0 + 1] + base;
        }
#pragma unroll
        for (int tp = 0; tp < 4; ++tp) {
            int rp = p0 + tp * 16 + quad * 4;
#pragma unroll
            for (int th = 0; th < 4; ++th) {
                int hh = h0 + th * 16 + m16;
                floatx4 bp4 = *(const floatx4*)(ABt + (size_t)hh * 2048 + 1024 + b * LPP + rp);
#pragma unroll
                for (int j = 0; j < 2; ++j) {
                    floatx4 a;
#pragma unroll
                    for (int i = 0; i < 4; ++i) a[i] = bp4[i] + av[j][th];
                    acc[j][tp][th] = a;
                }
            }
        }
    }
    __syncthreads();

    {
        const f16* Lr0 = proj + (size_t)ml0 * DDIM + quad * 8;
        const f16* Lr1 = Lr0 + DDIM;
        const f16* Prl[4];
#pragma unroll
        for (int tp = 0; tp < 4; ++tp)
            Prl[tp] = proj + (size_t)(1024 + b * LPP + p0 + tp * 16 + m16) * DDIM + quad * 8;

        f16x8 lv0 = *(const f16x8*)(Lr0);
        f16x8 lv1 = *(const f16x8*)(Lr1);
        f16x8 pv[4];
#pragma unroll
        for (int tp = 0; tp < 4; ++tp) pv[tp] = *(const f16x8*)(Prl[tp]);

        for (int ds = 0; ds < 8; ++ds) {
            f16x8 nlv0, nlv1, npv[4];
            if (ds < 7) {
                nlv0 = *(const f16x8*)(Lr0 + (ds + 1) * 32);
                nlv1 = *(const f16x8*)(Lr1 + (ds + 1) * 32);
#pragma unroll
                for (int tp = 0; tp < 4; ++tp)
                    npv[tp] = *(const f16x8*)(Prl[tp] + (ds + 1) * 32);
            }
            const char* wb = sm + (size_t)(ds * 2) * 8192 + (wh * 4) * 1024 + quad * 256 + m16 * 16;
            {
                f16x8 x[2][4];
#pragma unroll
                for (int tp = 0; tp < 4; ++tp) {
                    x[0][tp] = lv0 * pv[tp];
                    x[1][tp] = lv1 * pv[tp];
                }
#pragma unroll
                for (int th = 0; th < 4; ++th) {
                    f16x8 bf = *(const f16x8*)(wb + th * 1024);
#pragma unroll
                    for (int j = 0; j < 2; ++j)
#pragma unroll
                        for (int tp = 0; tp < 4; ++tp)
                            acc[j][tp][th] = __builtin_amdgcn_mfma_f32_16x16x32_f16(x[j][tp], bf, acc[j][tp][th], 0, 0, 0);
                }
            }
            {
                f16x8 x[2][4];
#pragma unroll
                for (int tp = 0; tp < 4; ++tp) {
                    x[0][tp] = habs8(lv0 - pv[tp]);
                    x[1][tp] = habs8(lv1 - pv[tp]);
                }
#pragma unroll
                for (int th = 0; th < 4; ++th) {
                    f16x8 bf = *(const f16x8*)(wb + 8192 + th * 1024);
#pragma unroll
                    for (int j = 0; j < 2; ++j)
#pragma unroll
                        for (int tp = 0; tp < 4; ++tp)
                            acc[j][tp][th] = __builtin_amdgcn_mfma_f32_16x16x32_f16(x[j][tp], bf, acc[j][tp][th], 0, 0, 0);
                }
            }
            lv0 = nlv0; lv1 = nlv1;
#pragma unroll
            for (int tp = 0; tp < 4; ++tp) pv[tp] = npv[tp];
        }
    }
    __syncthreads();

#pragma unroll
    for (int j = 0; j < 2; ++j) {
        char* h1s = sm + j * (256 * H1_STRIDE);
#pragma unroll
        for (int tp = 0; tp < 4; ++tp) {
#pragma unroll
            for (int i = 0; i < 4; ++i) {
                f16x4 hv;
#pragma unroll
                for (int th = 0; th < 4; ++th) hv[th] = (f16)gelu_f(acc[j][tp][th][i]);
                int p = p0 + tp * 16 + quad * 4 + i;
                *(f16x4*)(h1s + p * H1_STRIDE + m16 * 16 + wh * 8) = hv;
            }
        }
    }
    __syncthreads();

    float b2v[4], w3v[4];
#pragma unroll
    for (int th = 0; th < 4; ++th) {
        int g = h0 + th * 16 + m16;
        b2v[th] = b2[g];
        w3v[th] = W3[g];
    }
    floatx4 acc2[2][4][4];
#pragma unroll
    for (int j = 0; j < 2; ++j)
#pragma unroll
        for (int tp = 0; tp < 4; ++tp)
#pragma unroll
            for (int th = 0; th < 4; ++th) {
                floatx4 a;
                a[0] = a[1] = a[2] = a[3] = b2v[th];
                acc2[j][tp][th] = a;
            }
#pragma unroll
    for (int ks = 0; ks < 4; ++ks) {
        f16x8 af[2][4];
#pragma unroll
        for (int j = 0; j < 2; ++j)
#pragma unroll
            for (int tp = 0; tp < 4; ++tp)
                af[j][tp] = *(const f16x8*)(sm + j * (256 * H1_STRIDE) +
                                            (p0 + tp * 16 + m16) * H1_STRIDE + ks * 64 + quad * 16);
#pragma unroll
        for (int th = 0; th < 4; ++th) {
            f16x8 bf = *(const f16x8*)(w2g + (size_t)(((ks * 8 + wh * 4 + th) * 4 + quad) * 16 + m16) * 8);
#pragma unroll
            for (int j = 0; j < 2; ++j)
#pragma unroll
                for (int tp = 0; tp < 4; ++tp)
                    acc2[j][tp][th] = __builtin_amdgcn_mfma_f32_16x16x32_f16(af[j][tp], bf, acc2[j][tp][th], 0, 0, 0);
        }
    }

#pragma unroll
    for (int j = 0; j < 2; ++j) {
        float part[16];
#pragma unroll
        for (int q = 0; q < 16; ++q) part[q] = 0.f;
#pragma unroll
        for (int tp = 0; tp < 4; ++tp)
#pragma unroll
            for (int th = 0; th < 4; ++th)
#pragma unroll
                for (int i = 0; i < 4; ++i)
                    part[tp * 4 + i] += w3v[th] * gelu_f(acc2[j][tp][th][i]);
#pragma unroll
        for (int mask = 1; mask <= 8; mask <<= 1)
#pragma unroll
            for (int q = 0; q < 16; ++q) part[q] += __shfl_xor(part[q], mask, 64);
        if (m16 == 0) {
#pragma unroll
            for (int tp = 0; tp < 4; ++tp)
#pragma unroll
                for (int i = 0; i < 4; ++i)
                    atomicAdd(&plog[j * 256 + p0 + tp * 16 + quad * 4 + i], part[tp * 4 + i]);
        }
    }
    __syncthreads();

    if (tid < 512) {
        int j = tid >> 8, p = tid & 255;
        int ml = ml0 + j;
        float pl;
        if (l_pad[ml] != 0) {
            pl = -20.f;
        } else {
            pl = plog[tid] + b3[0];
            if (__builtin_isnan(pl)) pl = 0.f;
            else if (__builtin_isinf(pl)) pl = pl > 0.f ? 20.f : -20.f;
            if (p_pad[b * LPP + p] != 0) pl = -20.f;
        }
        outPL[(size_t)ml * LPP + p] = pl;
        outPR[(size_t)ml * LPP + p] = sigmoid_f(pl);
    }
}

// ---------------------------------------------------------------------------
// Top-k pipeline: 2-level radix select (8+8 bits of okey) parallelized over
// 64 blocks/batch, then exp-sum of the selected set. Scratch layout (ints):
//   hist0[b][256] | hist1[b][256] | sel[b][4] = {pref0,rem0,pref1,rem1}
//   S1[b], S2[b] (floats, atomic-accumulated)
// ---------------------------------------------------------------------------
#define TK_H0(b) (tk + (b) * 256)
#define TK_H1(b) (tk + 1024 + (b) * 256)
#define TK_SEL(b) (tk + 2048 + (b) * 4)
#define TK_S1(b) ((float*)(tk + 2064) + (b))
#define TK_S2(b) ((float*)(tk + 2068 + 12) + (b))  // keep 16B apart
#define TK_INTS 2096

__global__ __launch_bounds__(256) void tk_hist0(const float* __restrict__ pl,
                                                int* __restrict__ tk) {
    __shared__ int h[256];
    int tid = threadIdx.x, b = blockIdx.y;
    h[tid] = 0;
    __syncthreads();
    float4 t = ((const float4*)(pl + (size_t)b * 65536 + blockIdx.x * 1024))[tid];
#pragma unroll
    for (int c = 0; c < 4; ++c) atomicAdd(&h[okey((&t.x)[c]) >> 24], 1);
    __syncthreads();
    if (h[tid]) atomicAdd(&TK_H0(b)[tid], h[tid]);
}

// level: 0 -> select on hist0 with K=100 into sel[0..1]; 1 -> on hist1, K=rem0
__global__ __launch_bounds__(256) void tk_sel(int* __restrict__ tk, int level) {
    __shared__ int s[257];
    int tid = threadIdx.x, b = blockIdx.x;
    const int* hsrc = level ? TK_H1(b) : TK_H0(b);
    int K = level ? TK_SEL(b)[1] : 100;
    s[tid] = hsrc[tid];
    __syncthreads();
    for (int off = 1; off < 256; off <<= 1) {
        int v = (tid + off < 256) ? s[tid + off] : 0;
        __syncthreads();
        s[tid] += v;
        __syncthreads();
    }
    int nxt = (tid < 255) ? s[tid + 1] : 0;
    if (s[tid] >= K && nxt < K) {
        TK_SEL(b)[level * 2] = tid;
        TK_SEL(b)[level * 2 + 1] = K - nxt;
    }
}

__global__ __launch_bounds__(256) void tk_pass1(const float* __restrict__ pl,
                                                int* __restrict__ tk) {
    __shared__ int h[256];
    __shared__ float red[8];
    int tid = threadIdx.x, b = blockIdx.y;
    int lane = tid & 63, wv = tid >> 6;
    unsigned pref0 = (unsigned)TK_SEL(b)[0];
    h[tid] = 0;
    __syncthreads();
    float4 t = ((const float4*)(pl + (size_t)b * 65536 + blockIdx.x * 1024))[tid];
    float s1 = 0.f, s2 = 0.f;
#pragma unroll
    for (int c = 0; c < 4; ++c) {
        float v = (&t.x)[c];
        unsigned key = okey(v);
        unsigned hi = key >> 24;
        if (hi > pref0) {
            float e = __expf(v);
            s1 += e;
            s2 += e * v;
        } else if (hi == pref0) {
            atomicAdd(&h[(key >> 16) & 255], 1);
        }
    }
    __syncthreads();
    if (h[tid]) atomicAdd(&TK_H1(b)[tid], h[tid]);
    for (int off = 32; off > 0; off >>= 1) {
        s1 += __shfl_xor(s1, off, 64);
        s2 += __shfl_xor(s2, off, 64);
    }
    if (lane == 0) { red[wv] = s1; red[4 + wv] = s2; }
    __syncthreads();
    if (tid == 0) {
        float a = red[0] + red[1] + red[2] + red[3];
        float bsum = red[4] + red[5] + red[6] + red[7];
        if (a != 0.f) {
            atomicAdd(TK_S1(b), a);
            atomicAdd(TK_S2(b), bsum);
        }
    }
}

__global__ __launch_bounds__(256) void tk_pass2(const float* __restrict__ pl,
                                                int* __restrict__ tk) {
    __shared__ float red[8];
    int tid = threadIdx.x, b = blockIdx.y;
    int lane = tid & 63, wv = tid >> 6;
    unsigned pref0 = (unsigned)TK_SEL(b)[0];
    unsigned pref1 = (unsigned)TK_SEL(b)[2];
    float4 t = ((const float4*)(pl + (size_t)b * 65536 + blockIdx.x * 1024))[tid];
    float s1 = 0.f, s2 = 0.f;
#pragma unroll
    for (int c = 0; c < 4; ++c) {
        float v = (&t.x)[c];
        unsigned key = okey(v);
        if ((key >> 24) == pref0 && ((key >> 16) & 255) > pref1) {
            float e = __expf(v);
            s1 += e;
            s2 += e * v;
        }
    }
    for (int off = 32; off > 0; off >>= 1) {
        s1 += __shfl_xor(s1, off, 64);
        s2 += __shfl_xor(s2, off, 64);
    }
    if (lane == 0) { red[wv] = s1; red[4 + wv] = s2; }
    __syncthreads();
    if (tid == 0) {
        float a = red[0] + red[1] + red[2] + red[3];
        float bsum = red[4] + red[5] + red[6] + red[7];
        if (a != 0.f) {
            atomicAdd(TK_S1(b), a);
            atomicAdd(TK_S2(b), bsum);
        }
    }
}

__global__ __launch_bounds__(64) void tk_fin(int* __restrict__ tk,
                                             float* __restrict__ out) {
    int b = threadIdx.x;
    if (b >= BB) return;
    unsigned pref0 = (unsigned)TK_SEL(b)[0];
    unsigned pref1 = (unsigned)TK_SEL(b)[2];
    int rem1 = TK_SEL(b)[3];
    // boundary bin midpoint (16-bit prefix)
    unsigned key = (pref0 << 24) | (pref1 << 16) | 0x8000u;
    unsigned bits = (key & 0x80000000u) ? (key & 0x7fffffffu) : ~key;
    float vT = __uint_as_float(bits);
    float e = __expf(vT);
    float s1 = *TK_S1(b) + (float)rem1 * e;
    float s2 = *TK_S2(b) + (float)rem1 * e * vT;
    out[b] = s2 * __builtin_amdgcn_rcpf(s1);
}

// ---------------------------------------------------------------------------
extern "C" void kernel_launch(void* const* d_in, const int* in_sizes, int n_in,
                              void* d_out, int out_size, void* d_ws, size_t ws_size,
                              hipStream_t stream) {
    const float* l_tok = (const float*)d_in[0];
    const float* p_tok = (const float*)d_in[1];
    const int* l_pad = (const int*)d_in[2];
    const int* p_pad = (const int*)d_in[3];
    const float* Wl = (const float*)d_in[4];
    const float* bl = (const float*)d_in[5];
    const float* Wp = (const float*)d_in[6];
    const float* bp = (const float*)d_in[7];
    const float* W1 = (const float*)d_in[8];
    const float* b1 = (const float*)d_in[9];
    const float* W2 = (const float*)d_in[10];
    const float* b2 = (const float*)d_in[11];
    const float* W3 = (const float*)d_in[12];
    const float* b3 = (const float*)d_in[13];
    float* out = (float*)d_out;

    char* ws = (char*)d_ws;
    f16* proj = (f16*)ws;                                       // 1 MiB
    float* ABt = (float*)(ws + (size_t)2048 * 256 * 2);         // 1 MiB
    f16* w1g = (f16*)(ws + (size_t)2048 * 256 * 2 + (size_t)128 * 2048 * 4);  // 128 KiB
    f16* w2g = (f16*)((char*)w1g + (size_t)8192 * 16);          // 32 KiB
    int* tk = (int*)((char*)w2g + (size_t)2048 * 16);           // topk scratch

    hipMemsetAsync(tk, 0, TK_INTS * sizeof(int), stream);
    prep_proj<<<dim3(32, 4), 256, 0, stream>>>(l_tok, p_tok, Wl, Wp, bl, bp, proj);
    prep_ab<<<dim3(52, 2), 256, 0, stream>>>(proj, W1, W2, ABt, w1g, w2g);
    pair_main<<<dim3(LLL / 2, BB), 512, 0, stream>>>(proj, ABt, w1g, w2g, b1, b2, W3, b3,
                                                     l_pad, p_pad, out);
    const float* pl = out + 4;
    tk_hist0<<<dim3(64, BB), 256, 0, stream>>>(pl, tk);
    tk_sel<<<BB, 256, 0, stream>>>(tk, 0);
    tk_pass1<<<dim3(64, BB), 256, 0, stream>>>(pl, tk);
    tk_sel<<<BB, 256, 0, stream>>>(tk, 1);
    tk_pass2<<<dim3(64, BB), 256, 0, stream>>>(pl, tk);
    tk_fin<<<1, 64, 0, stream>>>(tk, out);
}